// Round 6
// baseline (602.890 us; speedup 1.0000x reference)
//
#include <hip/hip_runtime.h>
#include <math.h>

typedef unsigned short u16;
typedef unsigned int u32;
typedef u16 u16x4 __attribute__((ext_vector_type(4)));
typedef float f32x2 __attribute__((ext_vector_type(2)));
typedef float f32x4 __attribute__((ext_vector_type(4)));
typedef __bf16 bf16x8 __attribute__((ext_vector_type(8)));

__device__ __forceinline__ u16 f2bf(float f){
  u32 u = __builtin_bit_cast(u32, f);
  u32 r = u + 0x7FFFu + ((u >> 16) & 1u);
  return (u16)(r >> 16);
}
__device__ __forceinline__ float bf2f(u16 h){
  u32 u = ((u32)h) << 16;
  return __builtin_bit_cast(float, u);
}
__device__ __forceinline__ float ftanh(float x){
  float e = __expf(2.f*x);
  return 1.f - 2.f/(e+1.f);
}

typedef __attribute__((address_space(1))) const unsigned int gas_u32;
typedef __attribute__((address_space(3))) unsigned int las_u32;
__device__ __forceinline__ void gload_lds16(const void* g, void* l){
  __builtin_amdgcn_global_load_lds((gas_u32*)g, (las_u32*)l, 16, 0, 0);
}

// ---------------- converts ----------------
__global__ __launch_bounds__(256) void cvt_hi(const float* __restrict__ in, u16* __restrict__ out, int n4){
  int i = blockIdx.x*256 + threadIdx.x;
  if (i >= n4) return;
  f32x4 v = *(const f32x4*)(in + (size_t)i*4);
  u16x4 o;
  #pragma unroll
  for (int j=0;j<4;++j) o[j]=f2bf(v[j]);
  *(u16x4*)(out + (size_t)i*4) = o;
}

__global__ __launch_bounds__(256) void cvt_hilo(const float* __restrict__ in, u16* __restrict__ hi, u16* __restrict__ lo, int n4){
  int i = blockIdx.x*256 + threadIdx.x;
  if (i >= n4) return;
  f32x4 v = *(const f32x4*)(in + (size_t)i*4);
  u16x4 oh, ol;
  #pragma unroll
  for (int j=0;j<4;++j){ u16 h=f2bf(v[j]); oh[j]=h; ol[j]=f2bf(v[j]-bf2f(h)); }
  *(u16x4*)(hi + (size_t)i*4) = oh;
  *(u16x4*)(lo + (size_t)i*4) = ol;
}

// x,h -> cA_hi[:,0:3072] (bf16), x also -> x_lo
__global__ __launch_bounds__(256) void cvt_xh(const float* __restrict__ x, const float* __restrict__ h,
                                              u16* __restrict__ cA, u16* __restrict__ xlo){
  int b = blockIdx.y;
  int c0 = (blockIdx.x*256 + threadIdx.x)*4;
  f32x4 v;
  if (c0 < 1024) v = *(const f32x4*)(x + (size_t)b*1024 + c0);
  else           v = *(const f32x4*)(h + (size_t)b*2048 + (c0-1024));
  u16x4 hi4;
  #pragma unroll
  for (int j=0;j<4;++j) hi4[j]=f2bf(v[j]);
  *(u16x4*)(cA + (size_t)b*5120 + c0) = hi4;
  if (c0 < 1024){
    u16x4 lo4;
    #pragma unroll
    for (int j=0;j<4;++j) lo4[j]=f2bf(v[j]-bf2f(hi4[j]));
    *(u16x4*)(xlo + (size_t)b*1024 + c0) = lo4;
  }
}

// surfaced via dot-product identity (no atan2). bf16 into cA[:,3072:5120]; f32 only for flagged rows.
__global__ __launch_bounds__(256) void prep_surf(const float* __restrict__ xc, const float* __restrict__ dp,
                                                 const int* __restrict__ smap, float* __restrict__ Scmp,
                                                 u16* __restrict__ cA, int cap){
  int i = blockIdx.x*256 + threadIdx.x;   // over 4096*1024
  int b = i >> 10, h = i & 1023;
  f32x2 z = *(const f32x2*)(xc + 2*(size_t)i);
  f32x2 d = *(const f32x2*)(dp + 2*(size_t)i);
  float zx = z[0] + 1e-10f, dx = d[0] + 1e-10f;
  float hz = sqrtf(zx*zx + z[1]*z[1]);
  float hd = sqrtf(dx*dx + d[1]*d[1]);
  float cosd = (zx*dx + z[1]*d[1]) / fmaxf(hz*hd, 1e-30f);
  float T = 0.5f + 0.5f*cosd;
  float dmag = sqrtf(d[0]*d[0] + d[1]*d[1] + 1e-8f);
  float dscale = sqrtf(fminf(fmaxf(dmag, 1e-6f), 20.0f));
  float s = T * dscale / (dmag + 1e-8f);
  float o0 = d[0]*s, o1 = d[1]*s;
  u32 pk = (u32)f2bf(o0) | ((u32)f2bf(o1) << 16);
  *(u32*)&cA[(size_t)b*5120 + 3072 + 2*h] = pk;
  int p = smap[b];
  if (p >= 0 && p < cap)
    *(f32x2*)(Scmp + ((size_t)p*1024 + h)*2) = f32x2{o0, o1};
}

// rows with small temperature. out[0]=count(capped), out[1..]=rows; smap[b]=slot or -1
__global__ __launch_bounds__(256) void flag_rows(const float* __restrict__ bp, int* __restrict__ out,
                                                 int* __restrict__ smap, int cap){
  __shared__ int cnt;
  if (threadIdx.x==0) cnt=0;
  __syncthreads();
  for (int i=threadIdx.x; i<4096; i+=256){
    int p = -1;
    if (bp[i] < 0.04f){
      p = atomicAdd(&cnt,1);
      if (p < cap) out[1+p]=i;
    }
    smap[i] = p;
  }
  __syncthreads();
  if (threadIdx.x==0) out[0] = min(cnt, cap);
}

// write bias into rawfio rows that the split-K fixup will re-accumulate
__global__ __launch_bounds__(256) void fix_init(const int* __restrict__ smap, const int* __restrict__ cr,
    const float* __restrict__ b0, const float* __restrict__ b1, const float* __restrict__ b2,
    float* __restrict__ C){
  int b = blockIdx.x;
  int p = smap[b];
  if (p < 0 || p >= cr[0]) return;
  #pragma unroll
  for (int j0=0; j0<3072; j0+=256){
    int j = j0 + threadIdx.x;
    float bb = (j<1024) ? b0[j] : ((j<2048) ? b1[j-1024] : b2[j-2048]);
    C[(size_t)b*3072 + j] = bb;
  }
}

// ============ deep-pipelined GEMM: BK=32 tiles, 4-buffer ring, 2 phases/tile ============
// C[m][n] = sum_k A[m][k]*B[n][k] + bias(n).  BM=256, BN=NR*64.
// Stage stream: 2 stages/tile (A,B); prologue = tiles 0..2; each phase issues one stage of tile t+3.
// Ledger: at end-of-tile vmcnt, outstanding allowed = tiles t+2,t+3 -> NR4: 8 loads, NR2: 6 loads.
// LDS swizzle (involution, both sides): k-slot ^= (row>>1)&3.
#define STGA4(U) { int ut_ = (U) < NT ? (U) : NT-1; \
    const u16* s_ = Ah + aS + (size_t)ut_*32; \
    u16* d_ = sA + (ut_&3)*8192 + w8*512; \
    gload_lds16(s_, d_); gload_lds16(s_+aS2, d_+4096); }
#define STGB4(U) { int ut_ = (U) < NT ? (U) : NT-1; \
    const u16* s_ = Bh + bS + (size_t)ut_*32; \
    u16* d_ = sB + (ut_&3)*(NR*2048) + w8*512; \
    gload_lds16(s_, d_); \
    if constexpr (NR==4){ gload_lds16(s_+bS2, d_+4096); } }
#define PH4(MH, STG, DOW) do{ \
    bf16x8 af0 = *(const bf16x8*)(sAc + buf*16384 + abase + (MH)*4096 + 0*1024); \
    bf16x8 af1 = *(const bf16x8*)(sAc + buf*16384 + abase + (MH)*4096 + 1*1024); \
    bf16x8 af2 = *(const bf16x8*)(sAc + buf*16384 + abase + (MH)*4096 + 2*1024); \
    bf16x8 af3 = *(const bf16x8*)(sAc + buf*16384 + abase + (MH)*4096 + 3*1024); \
    if ((MH)==0){ _Pragma("unroll") for(int n_=0;n_<NR;++n_) \
      bfr[n_] = *(const bf16x8*)(sBc + buf*(NR*4096) + bbase + n_*1024); } \
    STG; \
    asm volatile("" ::: "memory"); \
    __builtin_amdgcn_s_barrier(); \
    asm volatile("s_waitcnt lgkmcnt(0)" ::: "memory"); \
    __builtin_amdgcn_sched_barrier(0); \
    __builtin_amdgcn_s_setprio(1); \
    _Pragma("unroll") for(int n_=0;n_<NR;++n_){ \
      acc[(MH)*4+0][n_] = __builtin_amdgcn_mfma_f32_16x16x32_bf16(af0, bfr[n_], acc[(MH)*4+0][n_],0,0,0); \
      acc[(MH)*4+1][n_] = __builtin_amdgcn_mfma_f32_16x16x32_bf16(af1, bfr[n_], acc[(MH)*4+1][n_],0,0,0); \
      acc[(MH)*4+2][n_] = __builtin_amdgcn_mfma_f32_16x16x32_bf16(af2, bfr[n_], acc[(MH)*4+2][n_],0,0,0); \
      acc[(MH)*4+3][n_] = __builtin_amdgcn_mfma_f32_16x16x32_bf16(af3, bfr[n_], acc[(MH)*4+3][n_],0,0,0); } \
    __builtin_amdgcn_s_setprio(0); \
    if (DOW){ asm volatile("s_waitcnt vmcnt(%0)" :: "i"(VN) : "memory"); } \
    asm volatile("" ::: "memory"); \
    __builtin_amdgcn_s_barrier(); \
    __builtin_amdgcn_sched_barrier(0); \
  }while(0)

template<int NR, bool OUTBF, int NB>
__global__ __launch_bounds__(512) void gemm4d(
    const u16* __restrict__ Ah, int lda,
    const u16* __restrict__ Bh, int ldb,
    const float* __restrict__ bias0, const float* __restrict__ bias1, const float* __restrict__ bias2,
    float* __restrict__ Cf, u16* __restrict__ Cb, int ldc, int K)
{
  constexpr int BN = NR*64;
  constexpr int VN = (NR==4) ? 8 : 6;
  __shared__ u16 sA[4*8192];          // 4 tile-bufs x [256][32] bf16 = 64 KB
  __shared__ u16 sB[4*NR*2048];       // 4 tile-bufs x [BN][32] bf16 (NR4: 64KB, NR2: 32KB)
  const char* sAc = (const char*)sA;
  const char* sBc = (const char*)sB;

  const int tid = threadIdx.x, lane = tid&63, w8 = tid>>6;
  const int wr = w8>>2, wc = w8&3;
  const int l16 = lane&15;

  // bijective XCD swizzle (grid sizes are multiples of 8)
  const int gx = gridDim.x, nwg = gx*gridDim.y;
  const int lin = blockIdx.y*gx + blockIdx.x;
  const int sw = (lin&7)*(nwg>>3) + (lin>>3);
  const int m0 = (sw / gx)*256, n0 = (sw % gx)*BN;

  // staging: thread stages chunk c=tid (row=tid>>2, lds slot=tid&3), pre-swizzled k-slot
  const int rowS = tid>>2;
  const int ksS  = (tid&3) ^ ((tid>>3)&3);
  const size_t aS  = (size_t)(m0 + rowS)*lda + ksS*8;
  const size_t aS2 = (size_t)128*lda;
  const size_t bS  = (size_t)(n0 + rowS)*ldb + ksS*8;
  const size_t bS2 = (size_t)128*ldb;

  // ds_read: swizzled k-slot = (lane>>4) ^ ((l16>>1)&3)
  const int aslot = (lane>>4) ^ ((l16>>1)&3);
  const int abase = (wr*128 + l16)*64 + aslot*16;       // bytes within A tile-buffer
  const int bbase = (wc*(NR*16) + l16)*64 + aslot*16;   // bytes within B tile-buffer

  f32x4 acc[8][NR];
  #pragma unroll
  for (int a=0;a<8;++a)
    #pragma unroll
    for (int b=0;b<NR;++b) acc[a][b] = f32x4{0.f,0.f,0.f,0.f};
  bf16x8 bfr[NR];

  const int NT = K>>5;

  // prologue: stage tiles 0,1,2 fully; wait until tile0 complete (tiles 1,2 stay in flight)
  STGA4(0) STGB4(0) STGA4(1) STGB4(1) STGA4(2) STGB4(2)
  asm volatile("s_waitcnt vmcnt(%0)" :: "i"(VN) : "memory");
  asm volatile("" ::: "memory");
  __builtin_amdgcn_s_barrier();
  __builtin_amdgcn_sched_barrier(0);

  for (int t=0; t<NT; ++t){
    const int buf = t&3;
    PH4(0, STGA4(t+3), false);   // ph0: mh0 MFMAs | stage A of tile t+3
    PH4(1, STGB4(t+3), true);    // ph1: mh1 MFMAs | stage B of tile t+3 | vmcnt(VN)
  }
  asm volatile("s_waitcnt vmcnt(0)" ::: "memory");  // drain before stores/endpgm

  #pragma unroll
  for (int mf=0; mf<8; ++mf){
    int grow = m0 + wr*128 + mf*16 + (lane>>4)*4;
    #pragma unroll
    for (int n=0; n<NR; ++n){
      int gcol = n0 + wc*(NR*16) + n*16 + l16;
      float bb;
      if constexpr(NB==3) bb = (gcol<1024) ? bias0[gcol] : ((gcol<2048) ? bias1[gcol-1024] : bias2[gcol-2048]);
      else bb = bias0[gcol];
      #pragma unroll
      for (int r2=0;r2<4;++r2){
        float v = acc[mf][n][r2] + bb;
        if constexpr(OUTBF) Cb[(size_t)(grow+r2)*ldc + gcol] = f2bf(v);
        else                Cf[(size_t)(grow+r2)*ldc + gcol] = v;
      }
    }
  }
}

// ---------------- fast 128^2 GEMM (m97 structure) — used for split-precision GEMM1 ----------------
template<bool SPLIT, bool OUTBF, int NB>
__global__ __launch_bounds__(256) void gemm_fast(
    const u16* __restrict__ Ah, int lda,
    const u16* __restrict__ Al, int ldal,
    const u16* __restrict__ Bh, int ldb,
    const u16* __restrict__ Bl,
    const float* __restrict__ bias0, const float* __restrict__ bias1, const float* __restrict__ bias2,
    float* __restrict__ Cf, u16* __restrict__ Cb, int ldc, int K)
{
  __shared__ u16 sAh[128*32];
  __shared__ u16 sBh[128*32];
  __shared__ u16 sAl[SPLIT?128*32:8];
  __shared__ u16 sBl[SPLIT?128*32:8];

  const int tid=threadIdx.x, lane=tid&63, w=tid>>6;

  const int gx = gridDim.x;
  const int nwg = gx * gridDim.y;
  const int lin = blockIdx.y*gx + blockIdx.x;
  const int sw = (lin & 7)*(nwg >> 3) + (lin >> 3);
  const int m0 = (sw / gx)*128, n0 = (sw % gx)*128;

  const int wm=(w>>1), wn=w&1, l16=lane&15, hi16=lane>>4;

  const int c0=(w*2+0)*64+lane, c1=c0+64;
  const int r0=c0>>2, sp0=(c0&3)^(r0&3);
  const int r1=c1>>2, sp1=(c1&3)^(r1&3);
  u16* lA0 = sAh + (w*2+0)*512; u16* lA1 = sAh + (w*2+1)*512;
  u16* lB0 = sBh + (w*2+0)*512; u16* lB1 = sBh + (w*2+1)*512;
  const u16* A0 = Ah + (size_t)(m0+r0)*lda + sp0*8;
  const u16* A1 = Ah + (size_t)(m0+r1)*lda + sp1*8;
  const u16* B0 = Bh + (size_t)(n0+r0)*ldb + sp0*8;
  const u16* B1 = Bh + (size_t)(n0+r1)*ldb + sp1*8;
  const u16 *A0l=nullptr,*A1l=nullptr,*B0l=nullptr,*B1l=nullptr;
  u16 *lA0l=nullptr,*lA1l=nullptr,*lB0l=nullptr,*lB1l=nullptr;
  if constexpr(SPLIT){
    A0l = Al + (size_t)(m0+r0)*ldal + sp0*8;
    A1l = Al + (size_t)(m0+r1)*ldal + sp1*8;
    B0l = Bl + (size_t)(n0+r0)*ldb  + sp0*8;
    B1l = Bl + (size_t)(n0+r1)*ldb  + sp1*8;
    lA0l = sAl + (w*2+0)*512; lA1l = sAl + (w*2+1)*512;
    lB0l = sBl + (w*2+0)*512; lB1l = sBl + (w*2+1)*512;
  }

  const int axor = (hi16 ^ (l16&3))*8;
  const int aoff = (wm*64 + l16)*32 + axor;
  const int boff = (wn*64 + l16)*32 + axor;

  f32x4 acc[4][4];
  #pragma unroll
  for (int a=0;a<4;++a)
    #pragma unroll
    for (int b=0;b<4;++b) acc[a][b] = f32x4{0.f,0.f,0.f,0.f};

  for (int k0=0; k0<K; k0+=32){
    gload_lds16(A0+k0, lA0);
    gload_lds16(A1+k0, lA1);
    gload_lds16(B0+k0, lB0);
    gload_lds16(B1+k0, lB1);
    if constexpr(SPLIT){
      gload_lds16(A0l+k0, lA0l);
      gload_lds16(A1l+k0, lA1l);
      gload_lds16(B0l+k0, lB0l);
      gload_lds16(B1l+k0, lB1l);
    }
    __syncthreads();
    bf16x8 fa[4], fb[4], fal[4], fbl[4];
    #pragma unroll
    for (int f=0; f<4; ++f){
      fa[f] = *(const bf16x8*)&sAh[aoff + f*512];
      fb[f] = *(const bf16x8*)&sBh[boff + f*512];
      if constexpr(SPLIT){
        fal[f] = *(const bf16x8*)&sAl[aoff + f*512];
        fbl[f] = *(const bf16x8*)&sBl[boff + f*512];
      }
    }
    #pragma unroll
    for (int fm=0; fm<4; ++fm){
      #pragma unroll
      for (int fn=0; fn<4; ++fn){
        acc[fm][fn] = __builtin_amdgcn_mfma_f32_16x16x32_bf16(fa[fm], fb[fn], acc[fm][fn], 0,0,0);
        if constexpr(SPLIT){
          acc[fm][fn] = __builtin_amdgcn_mfma_f32_16x16x32_bf16(fal[fm], fb[fn],  acc[fm][fn], 0,0,0);
          acc[fm][fn] = __builtin_amdgcn_mfma_f32_16x16x32_bf16(fa[fm],  fbl[fn], acc[fm][fn], 0,0,0);
        }
      }
    }
    __syncthreads();
  }

  #pragma unroll
  for (int fm=0; fm<4; ++fm){
    int grow = m0 + wm*64 + fm*16 + hi16*4;
    #pragma unroll
    for (int fn=0; fn<4; ++fn){
      int gcol = n0 + wn*64 + fn*16 + l16;
      float bb;
      if constexpr(NB==3) bb = (gcol<1024) ? bias0[gcol] : ((gcol<2048) ? bias1[gcol-1024] : bias2[gcol-2048]);
      else bb = bias0[gcol];
      #pragma unroll
      for (int r2=0;r2<4;++r2){
        float v = acc[fm][fn][r2] + bb;
        if constexpr(OUTBF) Cb[(size_t)(grow+r2)*ldc + gcol] = f2bf(v);
        else                Cf[(size_t)(grow+r2)*ldc + gcol] = v;
      }
    }
  }
}

// ---------------- fixup: precise 3-pass for flagged rows, SPLIT-K ----------------
#define LSTR 40
#define FIX_KC 8
#define FIX_KLEN 640
__global__ __launch_bounds__(256) void gemm_fix_sk(
    const float* __restrict__ Xs, const float* __restrict__ Hs,
    const float* __restrict__ Scmp, const int* __restrict__ smap,
    const float* __restrict__ W0, const float* __restrict__ W1, const float* __restrict__ W2,
    const int* __restrict__ cr, float* __restrict__ C)
{
  const int count = cr[0];
  const int m0 = blockIdx.y * 128;
  if (m0 >= count) return;
  const int* rows = cr + 1;
  const int kbeg = blockIdx.z * FIX_KLEN;
  const int kend = kbeg + FIX_KLEN;

  __shared__ u16 sAh[128*LSTR];
  __shared__ u16 sAl[128*LSTR];
  __shared__ u16 sBh[128*LSTR];
  __shared__ u16 sBl[128*LSTR];

  const int tid = threadIdx.x;
  const int n0 = blockIdx.x * 128;
  int seg = n0 >> 10;
  const float* W = (seg==0) ? W0 : (seg==1 ? W1 : W2);
  int nw = n0 & 1023;

  const int wave = tid >> 6, lane = tid & 63;
  const int wm = wave >> 1, wn = wave & 1;
  const int l16 = lane & 15, lk8 = (lane >> 4) * 8;

  f32x4 acc[4][4];
  #pragma unroll
  for (int a=0;a<4;++a)
    #pragma unroll
    for (int b=0;b<4;++b) acc[a][b] = f32x4{0.f,0.f,0.f,0.f};

  for (int k0 = kbeg; k0 < kend; k0 += 32){
    #pragma unroll
    for (int i=0;i<4;++i){
      int flat = tid + i*256;
      int r  = flat >> 3;
      int c4 = flat & 7;
      int kk = k0 + c4*4;
      int mrow = rows[min(m0 + r, count-1)];
      const float* srcA;
      if (kk < 1024)      srcA = Xs + (size_t)mrow*1024 + kk;
      else if (kk < 3072) srcA = Hs + (size_t)mrow*2048 + (kk - 1024);
      else                srcA = Scmp + (size_t)smap[mrow]*2048 + (kk - 3072);
      f32x4 va = *(const f32x4*)srcA;
      f32x4 vb = *(const f32x4*)(W + (size_t)(nw + r)*5120 + kk);
      u16x4 ah, bh, al, bl;
      #pragma unroll
      for (int j=0;j<4;++j){
        u16 hA = f2bf(va[j]); ah[j] = hA; al[j] = f2bf(va[j] - bf2f(hA));
        u16 hB = f2bf(vb[j]); bh[j] = hB; bl[j] = f2bf(vb[j] - bf2f(hB));
      }
      int o = r*LSTR + c4*4;
      *(u16x4*)&sAh[o] = ah;
      *(u16x4*)&sBh[o] = bh;
      *(u16x4*)&sAl[o] = al;
      *(u16x4*)&sBl[o] = bl;
    }
    __syncthreads();
    bf16x8 fah[4], fbh[4], fal[4], fbl[4];
    #pragma unroll
    for (int f=0; f<4; ++f){
      int ra  = (wm*64 + f*16 + l16)*LSTR + lk8;
      int rb2 = (wn*64 + f*16 + l16)*LSTR + lk8;
      fah[f] = *(const bf16x8*)&sAh[ra];
      fbh[f] = *(const bf16x8*)&sBh[rb2];
      fal[f] = *(const bf16x8*)&sAl[ra];
      fbl[f] = *(const bf16x8*)&sBl[rb2];
    }
    #pragma unroll
    for (int fm=0; fm<4; ++fm){
      #pragma unroll
      for (int fn=0; fn<4; ++fn){
        acc[fm][fn] = __builtin_amdgcn_mfma_f32_16x16x32_bf16(fah[fm], fbh[fn], acc[fm][fn], 0,0,0);
        acc[fm][fn] = __builtin_amdgcn_mfma_f32_16x16x32_bf16(fal[fm], fbh[fn], acc[fm][fn], 0,0,0);
        acc[fm][fn] = __builtin_amdgcn_mfma_f32_16x16x32_bf16(fah[fm], fbl[fn], acc[fm][fn], 0,0,0);
      }
    }
    __syncthreads();
  }

  #pragma unroll
  for (int fm=0; fm<4; ++fm){
    int trow = wm*64 + fm*16 + (lane>>4)*4;
    #pragma unroll
    for (int fn=0; fn<4; ++fn){
      int lcol = wn*64 + fn*16 + l16;
      #pragma unroll
      for (int r2=0;r2<4;++r2){
        int mi = m0 + trow + r2;
        if (mi < count){
          int mrow = rows[mi];
          atomicAdd(&C[(size_t)mrow*3072 + (n0 + lcol)], acc[fm][fn][r2]);
        }
      }
    }
  }
}

// ---------------- epilogue (transcendental-free gates) ----------------
__global__ __launch_bounds__(256) void epilogue(
    const float* __restrict__ rawfio, const u16* __restrict__ rawg,
    const float* __restrict__ c_prev, const float* __restrict__ d_prev,
    const float* __restrict__ b_prev, const float* __restrict__ theta,
    float* __restrict__ out)
{
  const int b = blockIdx.x;
  const int tid = threadIdx.x;
  float* Hout = out;
  float* Cout = out + (size_t)8388608;
  float* Dout = out + (size_t)16777216;
  float* Bout = out + (size_t)25165824;
  const float bp = b_prev[b];
  const float inv_t = 1.0f / (2.0f*bp + 1e-4f);
  float conv_acc = 0.f, emer_acc = 0.f;
  const size_t rb3 = (size_t)b*3072;
  const size_t rg = (size_t)b*2048;

  #pragma unroll
  for (int j=0;j<4;++j){
    int h = tid + j*256;
    float fr = rawfio[rb3 + h];
    float ir = rawfio[rb3 + 1024 + h];
    float og = rawfio[rb3 + 2048 + h];
    float g0 = bf2f(rawg[rg + h]);
    float g1 = bf2f(rawg[rg + 1024 + h]);

    float mx = fmaxf(fr, fmaxf(ir, og));
    float ef = __expf((fr-mx)*inv_t);
    float ei = __expf((ir-mx)*inv_t);
    float eo = __expf((og-mx)*inv_t);
    float inv_s = 1.0f/(ef+ei+eo);
    float ft = ef*inv_s, it = ei*inv_s, ot = eo*inv_s;

    f32x2 cp = *(const f32x2*)(c_prev + 2*((size_t)b*1024 + h));
    f32x2 dp = *(const f32x2*)(d_prev + 2*((size_t)b*1024 + h));

    float r0 = (1.f-ft)*cp[0], r1 = (1.f-ft)*cp[1];
    float rm2 = r0*r0 + r1*r1;
    conv_acc += rm2 + 1e-8f;
    float rmag = sqrtf(rm2 + 1e-8f);
    float cm = __expf(0.66666667f * __logf(rmag));
    float rx = r0 + 1e-10f;
    float hr = fmaxf(sqrtf(rx*rx + r1*r1), 1e-30f);
    float invhr = cm / hr;
    float comp0 = fminf(fmaxf(rx*invhr, -10.f), 10.f);
    float comp1 = fminf(fmaxf(r1*invhr, -10.f), 10.f);

    float d0 = dp[0] + 0.01f*comp0;
    float d1 = dp[1] + 0.01f*comp1;
    float dmn = sqrtf(d0*d0 + d1*d1 + 1e-8f);
    if (dmn > 20.f){ float sc = 20.f/dmn; d0*=sc; d1*=sc; }

    float gt0 = ftanh(g0), gt1 = ftanh(g1);
    float cu0 = ft*cp[0] + it*gt0;
    float cu1 = ft*cp[1] + it*gt1;
    float th = theta[h];
    float sth, cth;
    __sincosf(th, &sth, &cth);
    float c0 = cth*cu0 - sth*cu1;
    float c1 = sth*cu0 + cth*cu1;
    float cs0 = ftanh(c0), cs1 = ftanh(c1);
    float hr0 = ot*cs0, hr1 = ot*cs1;

    float hx = hr0 + 1e-10f, dx = d0 + 1e-10f;
    float hh = sqrtf(hx*hx + hr1*hr1);
    float hd = sqrtf(dx*dx + d1*d1);
    float cosd = (hx*dx + hr1*d1) / fmaxf(hh*hd, 1e-30f);
    float G = 0.5f + 0.5f*cosd;
    float h0 = G*hr0, h1 = G*hr1;
    emer_acc += h0*h0 + h1*h1 + 1e-8f;

    h0 = (h0==h0)?h0:0.f;  h1 = (h1==h1)?h1:0.f;
    c0 = (c0==c0)?c0:0.f;  c1 = (c1==c1)?c1:0.f;
    d0 = (d0==d0)?d0:0.f;  d1 = (d1==d1)?d1:0.f;

    size_t oi = 2*((size_t)b*1024 + h);
    *(f32x2*)(Hout+oi) = f32x2{h0,h1};
    *(f32x2*)(Cout+oi) = f32x2{c0,c1};
    *(f32x2*)(Dout+oi) = f32x2{d0,d1};
  }

  #pragma unroll
  for (int off=32; off; off>>=1){
    conv_acc += __shfl_down(conv_acc, off);
    emer_acc += __shfl_down(emer_acc, off);
  }
  __shared__ float sred[8];
  int wv = tid>>6, ln = tid&63;
  if (ln==0){ sred[wv]=conv_acc; sred[4+wv]=emer_acc; }
  __syncthreads();
  if (tid==0){
    float cv = sred[0]+sred[1]+sred[2]+sred[3];
    float em = sred[4]+sred[5]+sred[6]+sred[7];
    float bm = cv/(cv+em+1e-8f);
    float bt = 0.99f*bp + 0.01f*bm;
    bt = (bt==bt)?bt:0.5f;
    Bout[b] = bt;
  }
}

extern "C" void kernel_launch(void* const* d_in, const int* in_sizes, int n_in,
                              void* d_out, int out_size, void* d_ws, size_t ws_size,
                              hipStream_t stream)
{
  const float* x_t    = (const float*)d_in[0];
  const float* h_prev = (const float*)d_in[1];
  const float* c_prev = (const float*)d_in[2];
  const float* d_prev = (const float*)d_in[3];
  const float* b_prev = (const float*)d_in[4];
  const float* Wf_w   = (const float*)d_in[5];
  const float* Wf_b   = (const float*)d_in[6];
  const float* Wi_w   = (const float*)d_in[7];
  const float* Wi_b   = (const float*)d_in[8];
  const float* Wo_w   = (const float*)d_in[9];
  const float* Wo_b   = (const float*)d_in[10];
  const float* Wc_w   = (const float*)d_in[11];
  const float* Wc_b   = (const float*)d_in[12];
  const float* Wr_w   = (const float*)d_in[13];
  const float* Wr_b   = (const float*)d_in[14];
  const float* theta  = (const float*)d_in[15];

  char* W = (char*)d_ws;
  // OFF0: rawfio f32 [4096][3072]; xc f32 [4096][2048] aliased (dead before fio GEMM)
  float* rawfio = (float*)W;
  float* xc     = (float*)W;
  // OFF1 = 50331648: Wr_hi(4M)|Wr_lo(4M)|x_lo(8M) transient, later raw_g bf16 [4096][2048]
  u16*   Wr_hi  = (u16*)(W + 50331648);
  u16*   Wr_lo  = (u16*)(W + 50331648 + 4194304);
  u16*   x_lo   = (u16*)(W + 50331648 + 8388608);
  u16*   raw_g  = (u16*)(W + 50331648);
  // OFF2 = 67108864: cA bf16 [4096][5120]
  u16*   cA     = (u16*)(W + 67108864);
  // OFF3 = 109051904: WD3 bf16 [3072][5120] (fio), then Wc bf16 [2048][5120] reuse
  u16*   WD     = (u16*)(W + 109051904);
  // OFF4 = 140509184: idx (4097 ints) then smap (4096 ints)
  int*   idx    = (int*)(W + 140509184);
  int*   smap   = (int*)(W + 140509184 + 16388);
  // OFF5 = 140546048: surf_cmp f32 [cap][2048]
  float* Scmp   = (float*)(W + 140546048);
  long long avail = (long long)ws_size - 140546048LL;
  int cap = (int)(avail > 0 ? avail / 8192 : 0);
  if (cap > 1024) cap = 1024;

  dim3 blk(256);

  // 1. x,h -> cA[:,0:3072] + x_lo
  cvt_xh<<<dim3(3,4096), blk, 0, stream>>>(x_t, h_prev, cA, x_lo);
  // 2. Wr -> hi/lo
  cvt_hilo<<<2048, blk, 0, stream>>>(Wr_w, Wr_hi, Wr_lo, 524288);
  // 3. GEMM1 (split 3-pass): xc = x @ Wr^T + b
  gemm_fast<true,false,1><<<dim3(16,32), blk, 0, stream>>>(
      cA, 5120, x_lo, 1024, Wr_hi, 1024, Wr_lo,
      Wr_b, nullptr, nullptr, xc, nullptr, 2048, 1024);
  // 4. flag low-temperature rows
  flag_rows<<<1, blk, 0, stream>>>(b_prev, idx, smap, cap);
  // 5. surfaced -> cA[:,3072:5120] (+ compact f32 for flagged rows)
  prep_surf<<<16384, blk, 0, stream>>>(xc, d_prev, smap, Scmp, cA, cap);
  // 6. Wf,Wi,Wo -> WD3
  cvt_hi<<<5120, blk, 0, stream>>>(Wf_w, WD, 1310720);
  cvt_hi<<<5120, blk, 0, stream>>>(Wi_w, WD + (size_t)1024*5120, 1310720);
  cvt_hi<<<5120, blk, 0, stream>>>(Wo_w, WD + (size_t)2048*5120, 1310720);
  // 7. f/i/o merged (deep-pipeline 256x256), 192 blocks
  gemm4d<4,false,3><<<dim3(12,16), dim3(512), 0, stream>>>(
      cA, 5120, WD, 5120, Wf_b, Wi_b, Wo_b, rawfio, nullptr, 3072, 5120);
  // 8. bias-init flagged rows, then split-K precise fixup
  fix_init<<<4096, blk, 0, stream>>>(smap, idx, Wf_b, Wi_b, Wo_b, rawfio);
  gemm_fix_sk<<<dim3(24,8,FIX_KC), blk, 0, stream>>>(
      x_t, h_prev, Scmp, smap, Wf_w, Wi_w, Wo_w, idx, rawfio);
  // 9. Wc -> WD (reuse), g raw (deep-pipeline 256x128, 256 blocks, bf16 out)
  cvt_hi<<<10240, blk, 0, stream>>>(Wc_w, WD, 2621440);
  gemm4d<2,true,1><<<dim3(16,16), dim3(512), 0, stream>>>(
      cA, 5120, WD, 5120, Wc_b, nullptr, nullptr, nullptr, raw_g, 2048, 5120);
  // 10. epilogue
  epilogue<<<4096, blk, 0, stream>>>(rawfio, raw_g, c_prev, d_prev, b_prev, theta, (float*)d_out);
}

// Round 7
// 525.424 us; speedup vs baseline: 1.1474x; 1.1474x over previous
//
#include <hip/hip_runtime.h>
#include <math.h>

typedef unsigned short u16;
typedef unsigned int u32;
typedef u16 u16x4 __attribute__((ext_vector_type(4)));
typedef float f32x2 __attribute__((ext_vector_type(2)));
typedef float f32x4 __attribute__((ext_vector_type(4)));
typedef __bf16 bf16x8 __attribute__((ext_vector_type(8)));

__device__ __forceinline__ u16 f2bf(float f){
  u32 u = __builtin_bit_cast(u32, f);
  u32 r = u + 0x7FFFu + ((u >> 16) & 1u);
  return (u16)(r >> 16);
}
__device__ __forceinline__ float bf2f(u16 h){
  u32 u = ((u32)h) << 16;
  return __builtin_bit_cast(float, u);
}
__device__ __forceinline__ float ftanh(float x){
  float e = __expf(2.f*x);
  return 1.f - 2.f/(e+1.f);
}

typedef __attribute__((address_space(1))) const unsigned int gas_u32;
typedef __attribute__((address_space(3))) unsigned int las_u32;
__device__ __forceinline__ void gload_lds16(const void* g, void* l){
  __builtin_amdgcn_global_load_lds((gas_u32*)g, (las_u32*)l, 16, 0, 0);
}

// ---------------- converts ----------------
__global__ __launch_bounds__(256) void cvt_hi(const float* __restrict__ in, u16* __restrict__ out, int n4){
  int i = blockIdx.x*256 + threadIdx.x;
  if (i >= n4) return;
  f32x4 v = *(const f32x4*)(in + (size_t)i*4);
  u16x4 o;
  #pragma unroll
  for (int j=0;j<4;++j) o[j]=f2bf(v[j]);
  *(u16x4*)(out + (size_t)i*4) = o;
}

__global__ __launch_bounds__(256) void cvt_hilo(const float* __restrict__ in, u16* __restrict__ hi, u16* __restrict__ lo, int n4){
  int i = blockIdx.x*256 + threadIdx.x;
  if (i >= n4) return;
  f32x4 v = *(const f32x4*)(in + (size_t)i*4);
  u16x4 oh, ol;
  #pragma unroll
  for (int j=0;j<4;++j){ u16 h=f2bf(v[j]); oh[j]=h; ol[j]=f2bf(v[j]-bf2f(h)); }
  *(u16x4*)(hi + (size_t)i*4) = oh;
  *(u16x4*)(lo + (size_t)i*4) = ol;
}

// x,h -> cA_hi[:,0:3072] (bf16), x also -> x_lo
__global__ __launch_bounds__(256) void cvt_xh(const float* __restrict__ x, const float* __restrict__ h,
                                              u16* __restrict__ cA, u16* __restrict__ xlo){
  int b = blockIdx.y;
  int c0 = (blockIdx.x*256 + threadIdx.x)*4;
  f32x4 v;
  if (c0 < 1024) v = *(const f32x4*)(x + (size_t)b*1024 + c0);
  else           v = *(const f32x4*)(h + (size_t)b*2048 + (c0-1024));
  u16x4 hi4;
  #pragma unroll
  for (int j=0;j<4;++j) hi4[j]=f2bf(v[j]);
  *(u16x4*)(cA + (size_t)b*5120 + c0) = hi4;
  if (c0 < 1024){
    u16x4 lo4;
    #pragma unroll
    for (int j=0;j<4;++j) lo4[j]=f2bf(v[j]-bf2f(hi4[j]));
    *(u16x4*)(xlo + (size_t)b*1024 + c0) = lo4;
  }
}

// surfaced via dot-product identity (no atan2). bf16 into cA[:,3072:5120]; f32 only for flagged rows.
__global__ __launch_bounds__(256) void prep_surf(const float* __restrict__ xc, const float* __restrict__ dp,
                                                 const int* __restrict__ smap, float* __restrict__ Scmp,
                                                 u16* __restrict__ cA, int cap){
  int i = blockIdx.x*256 + threadIdx.x;   // over 4096*1024
  int b = i >> 10, h = i & 1023;
  f32x2 z = *(const f32x2*)(xc + 2*(size_t)i);
  f32x2 d = *(const f32x2*)(dp + 2*(size_t)i);
  float zx = z[0] + 1e-10f, dx = d[0] + 1e-10f;
  float hz = sqrtf(zx*zx + z[1]*z[1]);
  float hd = sqrtf(dx*dx + d[1]*d[1]);
  float cosd = (zx*dx + z[1]*d[1]) / fmaxf(hz*hd, 1e-30f);
  float T = 0.5f + 0.5f*cosd;
  float dmag = sqrtf(d[0]*d[0] + d[1]*d[1] + 1e-8f);
  float dscale = sqrtf(fminf(fmaxf(dmag, 1e-6f), 20.0f));
  float s = T * dscale / (dmag + 1e-8f);
  float o0 = d[0]*s, o1 = d[1]*s;
  u32 pk = (u32)f2bf(o0) | ((u32)f2bf(o1) << 16);
  *(u32*)&cA[(size_t)b*5120 + 3072 + 2*h] = pk;
  int p = smap[b];
  if (p >= 0 && p < cap)
    *(f32x2*)(Scmp + ((size_t)p*1024 + h)*2) = f32x2{o0, o1};
}

// rows with small temperature. out[0]=count(capped), out[1..]=rows; smap[b]=slot or -1
__global__ __launch_bounds__(256) void flag_rows(const float* __restrict__ bp, int* __restrict__ out,
                                                 int* __restrict__ smap, int cap){
  __shared__ int cnt;
  if (threadIdx.x==0) cnt=0;
  __syncthreads();
  for (int i=threadIdx.x; i<4096; i+=256){
    int p = -1;
    if (bp[i] < 0.04f){
      p = atomicAdd(&cnt,1);
      if (p < cap) out[1+p]=i;
    }
    smap[i] = p;
  }
  __syncthreads();
  if (threadIdx.x==0) out[0] = min(cnt, cap);
}

// write bias into rawfio rows that the split-K fixup will re-accumulate
__global__ __launch_bounds__(256) void fix_init(const int* __restrict__ smap, const int* __restrict__ cr,
    const float* __restrict__ b0, const float* __restrict__ b1, const float* __restrict__ b2,
    float* __restrict__ C){
  int b = blockIdx.x;
  int p = smap[b];
  if (p < 0 || p >= cr[0]) return;
  #pragma unroll
  for (int j0=0; j0<3072; j0+=256){
    int j = j0 + threadIdx.x;
    float bb = (j<1024) ? b0[j] : ((j<2048) ? b1[j-1024] : b2[j-2048]);
    C[(size_t)b*3072 + j] = bb;
  }
}

// ============ 8-phase 256-wide GEMM (R5 version, known-good) ============
#define LDA8(BUF,H,MH,J) (*(const bf16x8*)(sAc + ((BUF)*2+(H))*16384 + abase + (MH)*4096 + (J)*1024))
#define LDB8(BUF,H,N)    (*(const bf16x8*)(sBc + ((BUF)*2+(H))*BHTB + bbase + (N)*1024))
#define STG_A8(BUF,H,TT) { const u16* s_ = Ah + aS + (size_t)(TT)*64 + (H)*32; \
    gload_lds16(s_, dA + ((BUF)*2+(H))*8192); \
    gload_lds16(s_ + aS2, dA + ((BUF)*2+(H))*8192 + 4096); }
#define STG_B8(BUF,H,TT) { const u16* s_ = Bh + bS + (size_t)(TT)*64 + (H)*32; \
    gload_lds16(s_, dB + ((BUF)*2+(H))*(BHTB/2)); \
    if constexpr (NR==4){ gload_lds16(s_ + bS2, dB + ((BUF)*2+(H))*(BHTB/2) + 4096); } }
#define PH8(BUF,H,MH,RB,STG,DOW) do{ \
    bf16x8 af0 = LDA8(BUF,H,MH,0), af1 = LDA8(BUF,H,MH,1), af2 = LDA8(BUF,H,MH,2), af3 = LDA8(BUF,H,MH,3); \
    if (RB){ _Pragma("unroll") for(int n_=0;n_<NR;++n_) bfr[n_] = LDB8(BUF,H,n_); } \
    STG; \
    asm volatile("" ::: "memory"); \
    __builtin_amdgcn_s_barrier(); \
    asm volatile("s_waitcnt lgkmcnt(0)" ::: "memory"); \
    __builtin_amdgcn_sched_barrier(0); \
    __builtin_amdgcn_s_setprio(1); \
    _Pragma("unroll") for(int n_=0;n_<NR;++n_){ \
      acc[(MH)*4+0][n_] = __builtin_amdgcn_mfma_f32_16x16x32_bf16(af0, bfr[n_], acc[(MH)*4+0][n_],0,0,0); \
      acc[(MH)*4+1][n_] = __builtin_amdgcn_mfma_f32_16x16x32_bf16(af1, bfr[n_], acc[(MH)*4+1][n_],0,0,0); \
      acc[(MH)*4+2][n_] = __builtin_amdgcn_mfma_f32_16x16x32_bf16(af2, bfr[n_], acc[(MH)*4+2][n_],0,0,0); \
      acc[(MH)*4+3][n_] = __builtin_amdgcn_mfma_f32_16x16x32_bf16(af3, bfr[n_], acc[(MH)*4+3][n_],0,0,0); } \
    __builtin_amdgcn_s_setprio(0); \
    if (DOW) { asm volatile("s_waitcnt vmcnt(%0)" :: "i"(VN) : "memory"); } \
    asm volatile("" ::: "memory"); \
    __builtin_amdgcn_s_barrier(); \
    __builtin_amdgcn_sched_barrier(0); \
  }while(0)

template<int NR, bool OUTBF, int NB>
__global__ __launch_bounds__(512) void gemm8p(
    const u16* __restrict__ Ah, int lda,
    const u16* __restrict__ Bh, int ldb,
    const float* __restrict__ bias0, const float* __restrict__ bias1, const float* __restrict__ bias2,
    float* __restrict__ Cf, u16* __restrict__ Cb, int ldc, int K)
{
  constexpr int BN   = NR*64;
  constexpr int BHTB = BN*64;
  constexpr int VN   = (NR==4) ? 4 : 3;
  __shared__ u16 sA[4*8192];
  __shared__ u16 sB[4*(NR*2048)];
  const char* sAc = (const char*)sA;
  const char* sBc = (const char*)sB;

  const int tid = threadIdx.x, lane = tid&63, w8 = tid>>6;
  const int wr = w8>>2, wc = w8&3;
  const int l16 = lane&15;

  const int gx = gridDim.x, nwg = gx*gridDim.y;
  const int lin = blockIdx.y*gx + blockIdx.x;
  const int sw = (lin&7)*(nwg>>3) + (lin>>3);
  const int m0 = (sw / gx)*256, n0 = (sw % gx)*BN;

  const int rowS  = tid>>2;
  const int ksS   = (tid&3) ^ ((tid>>3)&3);
  const size_t aS = (size_t)(m0 + rowS)*lda + ksS*8;
  const size_t aS2= (size_t)128*lda;
  const size_t bS = (size_t)(n0 + rowS)*ldb + ksS*8;
  const size_t bS2= (size_t)128*ldb;
  u16* dA = sA + w8*512;
  u16* dB = sB + w8*512;

  const int aslot = (lane>>4) ^ ((l16>>1)&3);
  const int abase = (wr*128 + l16)*64 + aslot*16;
  const int bbase = (wc*(NR*16) + l16)*64 + aslot*16;

  f32x4 acc[8][NR];
  #pragma unroll
  for (int a=0;a<8;++a)
    #pragma unroll
    for (int b=0;b<NR;++b) acc[a][b] = f32x4{0.f,0.f,0.f,0.f};
  bf16x8 bfr[NR];

  const int NT = K>>6, NITER = K>>7;

  STG_A8(0,0,0) STG_B8(0,0,0) STG_A8(0,1,0) STG_B8(0,1,0) STG_A8(1,0,1) STG_B8(1,0,1)
  asm volatile("s_waitcnt vmcnt(%0)" :: "i"(VN) : "memory");
  asm volatile("" ::: "memory");
  __builtin_amdgcn_s_barrier();
  __builtin_amdgcn_sched_barrier(0);

  for (int i=0; i<NITER; ++i){
    const int t1 = 2*i+1;
    const int ta = min(2*i+2, NT-1);
    const int tb = min(2*i+3, NT-1);
    PH8(0,0,0,true,  STG_A8(1,1,t1), false);
    PH8(0,0,1,false, STG_B8(1,1,t1), false);
    PH8(0,1,0,true,  STG_A8(0,0,ta), false);
    PH8(0,1,1,false, STG_B8(0,0,ta), true);
    PH8(1,0,0,true,  STG_A8(0,1,ta), false);
    PH8(1,0,1,false, STG_B8(0,1,ta), false);
    PH8(1,1,0,true,  STG_A8(1,0,tb), false);
    PH8(1,1,1,false, STG_B8(1,0,tb), true);
  }
  asm volatile("s_waitcnt vmcnt(0)" ::: "memory");

  #pragma unroll
  for (int mf=0; mf<8; ++mf){
    int grow = m0 + wr*128 + mf*16 + (lane>>4)*4;
    #pragma unroll
    for (int n=0; n<NR; ++n){
      int gcol = n0 + wc*(NR*16) + n*16 + l16;
      float bb;
      if constexpr(NB==3) bb = (gcol<1024) ? bias0[gcol] : ((gcol<2048) ? bias1[gcol-1024] : bias2[gcol-2048]);
      else bb = bias0[gcol];
      #pragma unroll
      for (int r2=0;r2<4;++r2){
        float v = acc[mf][n][r2] + bb;
        if constexpr(OUTBF) Cb[(size_t)(grow+r2)*ldc + gcol] = f2bf(v);
        else                Cf[(size_t)(grow+r2)*ldc + gcol] = v;
      }
    }
  }
}

// ============ gemm128: BM=128 BN=256 BK=32, 3-buf ring, 1 phase/tile, 16(48) MFMA/phase ============
// SPLIT: 3-pass hi/lo (fp32-accurate) -> 48 MFMA/phase, LDS 144KB, vmcnt(6).
// plain: 16 MFMA/phase, LDS 72KB, vmcnt(3). Stage dst ring never clamped; src tile clamped.
#define STG128(USRC, BW) do{ int u_=(USRC)<NT?(USRC):NT-1; \
    { const u16* s_=Ah+aS+(size_t)u_*32; gload_lds16(s_, sA+(BW)*4096+ldsb); } \
    { const u16* s_=Bh+bS+(size_t)u_*32; gload_lds16(s_, sB+(BW)*8192+ldsb); \
      gload_lds16(s_+bS2, sB+(BW)*8192+4096+ldsb); } \
    if constexpr(SPLIT){ \
      const u16* s2_=Al+aSl+(size_t)u_*32; gload_lds16(s2_, sAl+(BW)*4096+ldsb); \
      const u16* s3_=Bl+bS+(size_t)u_*32;  gload_lds16(s3_, sBl+(BW)*8192+ldsb); \
      gload_lds16(s3_+bS2, sBl+(BW)*8192+4096+ldsb); } \
  }while(0)

template<bool SPLIT, bool OUTBF>
__global__ __launch_bounds__(512) void gemm128(
    const u16* __restrict__ Ah, int lda,
    const u16* __restrict__ Al, int ldal,
    const u16* __restrict__ Bh, int ldb,
    const u16* __restrict__ Bl,
    const float* __restrict__ bias0,
    float* __restrict__ Cf, u16* __restrict__ Cb, int ldc, int K)
{
  constexpr int VN = SPLIT ? 6 : 3;
  __shared__ u16 sA [3*4096];
  __shared__ u16 sB [3*8192];
  __shared__ u16 sAl[SPLIT?3*4096:8];
  __shared__ u16 sBl[SPLIT?3*8192:8];

  const int tid=threadIdx.x, lane=tid&63, w8=tid>>6;
  const int wr=w8>>2, wc=w8&3, l16=lane&15;

  const int gx=gridDim.x, nwg=gx*gridDim.y;
  const int lin=blockIdx.y*gx+blockIdx.x;
  const int sw=(lin&7)*(nwg>>3)+(lin>>3);
  const int m0=(sw/gx)*128, n0=(sw%gx)*256;

  const int rowS=tid>>2;
  const int ksS=(tid&3)^((tid>>3)&3);
  const size_t aS =(size_t)(m0+rowS)*lda  + ksS*8;
  const size_t aSl=(size_t)(m0+rowS)*(size_t)ldal + ksS*8;
  const size_t bS =(size_t)(n0+rowS)*ldb  + ksS*8;
  const size_t bS2=(size_t)128*ldb;
  const int ldsb = w8*512;   // u16 units, wave-uniform

  const int aslot=(lane>>4)^((l16>>1)&3);
  const int abase=(wr*64+l16)*64 + aslot*16;   // bytes within 8KB A buf
  const int bbase=(wc*64+l16)*64 + aslot*16;   // bytes within 16KB B buf

  f32x4 acc[4][4];
  #pragma unroll
  for (int a=0;a<4;++a)
    #pragma unroll
    for (int b=0;b<4;++b) acc[a][b] = f32x4{0.f,0.f,0.f,0.f};

  const int NT = K>>5;

  // prologue: stage tiles 0,1; wait tile0 (tile1 stays in flight)
  STG128(0,0); STG128(1,1);
  asm volatile("s_waitcnt vmcnt(%0)" :: "i"(VN) : "memory");
  asm volatile("" ::: "memory");
  __builtin_amdgcn_s_barrier();
  __builtin_amdgcn_sched_barrier(0);

  int bufR = 0;
  for (int t=0; t<NT; ++t){
    int bufW = bufR+2; if (bufW>=3) bufW-=3;
    const char* sAc=(const char*)sA  + bufR*8192;
    const char* sBc=(const char*)sB  + bufR*16384;
    const char* sAlc=(const char*)sAl + bufR*8192;
    const char* sBlc=(const char*)sBl + bufR*16384;
    bf16x8 af[4], bf[4], afl[4], bfl[4];
    #pragma unroll
    for (int f=0; f<4; ++f){
      af[f] = *(const bf16x8*)(sAc + abase + f*1024);
      bf[f] = *(const bf16x8*)(sBc + bbase + f*1024);
      if constexpr(SPLIT){
        afl[f] = *(const bf16x8*)(sAlc + abase + f*1024);
        bfl[f] = *(const bf16x8*)(sBlc + bbase + f*1024);
      }
    }
    STG128(t+2, bufW);
    asm volatile("" ::: "memory");
    __builtin_amdgcn_s_barrier();
    asm volatile("s_waitcnt lgkmcnt(0)" ::: "memory");
    __builtin_amdgcn_sched_barrier(0);
    __builtin_amdgcn_s_setprio(1);
    #pragma unroll
    for (int mf=0; mf<4; ++mf){
      #pragma unroll
      for (int nf=0; nf<4; ++nf){
        acc[mf][nf] = __builtin_amdgcn_mfma_f32_16x16x32_bf16(af[mf], bf[nf], acc[mf][nf],0,0,0);
        if constexpr(SPLIT){
          acc[mf][nf] = __builtin_amdgcn_mfma_f32_16x16x32_bf16(afl[mf], bf[nf],  acc[mf][nf],0,0,0);
          acc[mf][nf] = __builtin_amdgcn_mfma_f32_16x16x32_bf16(af[mf],  bfl[nf], acc[mf][nf],0,0,0);
        }
      }
    }
    __builtin_amdgcn_s_setprio(0);
    asm volatile("s_waitcnt vmcnt(%0)" :: "i"(VN) : "memory");
    asm volatile("" ::: "memory");
    __builtin_amdgcn_s_barrier();
    __builtin_amdgcn_sched_barrier(0);
    bufR = (bufR==2) ? 0 : bufR+1;
  }
  asm volatile("s_waitcnt vmcnt(0)" ::: "memory");

  #pragma unroll
  for (int mf=0; mf<4; ++mf){
    int grow = m0 + wr*64 + mf*16 + (lane>>4)*4;
    #pragma unroll
    for (int nf=0; nf<4; ++nf){
      int gcol = n0 + wc*64 + nf*16 + l16;
      float bb = bias0[gcol];
      #pragma unroll
      for (int r2=0;r2<4;++r2){
        float v = acc[mf][nf][r2] + bb;
        if constexpr(OUTBF) Cb[(size_t)(grow+r2)*ldc + gcol] = f2bf(v);
        else                Cf[(size_t)(grow+r2)*ldc + gcol] = v;
      }
    }
  }
}

// ---------------- fixup: precise 3-pass for flagged rows, SPLIT-K ----------------
#define LSTR 40
#define FIX_KC 16
#define FIX_KLEN 320
__global__ __launch_bounds__(256) void gemm_fix_sk(
    const float* __restrict__ Xs, const float* __restrict__ Hs,
    const float* __restrict__ Scmp, const int* __restrict__ smap,
    const float* __restrict__ W0, const float* __restrict__ W1, const float* __restrict__ W2,
    const int* __restrict__ cr, float* __restrict__ C)
{
  const int count = cr[0];
  const int m0 = blockIdx.y * 128;
  if (m0 >= count) return;
  const int* rows = cr + 1;
  const int kbeg = blockIdx.z * FIX_KLEN;
  const int kend = kbeg + FIX_KLEN;

  __shared__ u16 sAh[128*LSTR];
  __shared__ u16 sAl[128*LSTR];
  __shared__ u16 sBh[128*LSTR];
  __shared__ u16 sBl[128*LSTR];

  const int tid = threadIdx.x;
  const int n0 = blockIdx.x * 128;
  int seg = n0 >> 10;
  const float* W = (seg==0) ? W0 : (seg==1 ? W1 : W2);
  int nw = n0 & 1023;

  const int wave = tid >> 6, lane = tid & 63;
  const int wm = wave >> 1, wn = wave & 1;
  const int l16 = lane & 15, lk8 = (lane >> 4) * 8;

  f32x4 acc[4][4];
  #pragma unroll
  for (int a=0;a<4;++a)
    #pragma unroll
    for (int b=0;b<4;++b) acc[a][b] = f32x4{0.f,0.f,0.f,0.f};

  for (int k0 = kbeg; k0 < kend; k0 += 32){
    #pragma unroll
    for (int i=0;i<4;++i){
      int flat = tid + i*256;
      int r  = flat >> 3;
      int c4 = flat & 7;
      int kk = k0 + c4*4;
      int mrow = rows[min(m0 + r, count-1)];
      const float* srcA;
      if (kk < 1024)      srcA = Xs + (size_t)mrow*1024 + kk;
      else if (kk < 3072) srcA = Hs + (size_t)mrow*2048 + (kk - 1024);
      else                srcA = Scmp + (size_t)smap[mrow]*2048 + (kk - 3072);
      f32x4 va = *(const f32x4*)srcA;
      f32x4 vb = *(const f32x4*)(W + (size_t)(nw + r)*5120 + kk);
      u16x4 ah, bh, al, bl;
      #pragma unroll
      for (int j=0;j<4;++j){
        u16 hA = f2bf(va[j]); ah[j] = hA; al[j] = f2bf(va[j] - bf2f(hA));
        u16 hB = f2bf(vb[j]); bh[j] = hB; bl[j] = f2bf(vb[j] - bf2f(hB));
      }
      int o = r*LSTR + c4*4;
      *(u16x4*)&sAh[o] = ah;
      *(u16x4*)&sBh[o] = bh;
      *(u16x4*)&sAl[o] = al;
      *(u16x4*)&sBl[o] = bl;
    }
    __syncthreads();
    bf16x8 fah[4], fbh[4], fal[4], fbl[4];
    #pragma unroll
    for (int f=0; f<4; ++f){
      int ra  = (wm*64 + f*16 + l16)*LSTR + lk8;
      int rb2 = (wn*64 + f*16 + l16)*LSTR + lk8;
      fah[f] = *(const bf16x8*)&sAh[ra];
      fbh[f] = *(const bf16x8*)&sBh[rb2];
      fal[f] = *(const bf16x8*)&sAl[ra];
      fbl[f] = *(const bf16x8*)&sBl[rb2];
    }
    #pragma unroll
    for (int fm=0; fm<4; ++fm){
      #pragma unroll
      for (int fn=0; fn<4; ++fn){
        acc[fm][fn] = __builtin_amdgcn_mfma_f32_16x16x32_bf16(fah[fm], fbh[fn], acc[fm][fn], 0,0,0);
        acc[fm][fn] = __builtin_amdgcn_mfma_f32_16x16x32_bf16(fal[fm], fbh[fn], acc[fm][fn], 0,0,0);
        acc[fm][fn] = __builtin_amdgcn_mfma_f32_16x16x32_bf16(fah[fm], fbl[fn], acc[fm][fn], 0,0,0);
      }
    }
    __syncthreads();
  }

  #pragma unroll
  for (int fm=0; fm<4; ++fm){
    int trow = wm*64 + fm*16 + (lane>>4)*4;
    #pragma unroll
    for (int fn=0; fn<4; ++fn){
      int lcol = wn*64 + fn*16 + l16;
      #pragma unroll
      for (int r2=0;r2<4;++r2){
        int mi = m0 + trow + r2;
        if (mi < count){
          int mrow = rows[mi];
          atomicAdd(&C[(size_t)mrow*3072 + (n0 + lcol)], acc[fm][fn][r2]);
        }
      }
    }
  }
}

// ---------------- epilogue (transcendental-free gates) ----------------
__global__ __launch_bounds__(256) void epilogue(
    const float* __restrict__ rawfio, const u16* __restrict__ rawg,
    const float* __restrict__ c_prev, const float* __restrict__ d_prev,
    const float* __restrict__ b_prev, const float* __restrict__ theta,
    float* __restrict__ out)
{
  const int b = blockIdx.x;
  const int tid = threadIdx.x;
  float* Hout = out;
  float* Cout = out + (size_t)8388608;
  float* Dout = out + (size_t)16777216;
  float* Bout = out + (size_t)25165824;
  const float bp = b_prev[b];
  const float inv_t = 1.0f / (2.0f*bp + 1e-4f);
  float conv_acc = 0.f, emer_acc = 0.f;
  const size_t rb3 = (size_t)b*3072;
  const size_t rg = (size_t)b*2048;

  #pragma unroll
  for (int j=0;j<4;++j){
    int h = tid + j*256;
    float fr = rawfio[rb3 + h];
    float ir = rawfio[rb3 + 1024 + h];
    float og = rawfio[rb3 + 2048 + h];
    float g0 = bf2f(rawg[rg + h]);
    float g1 = bf2f(rawg[rg + 1024 + h]);

    float mx = fmaxf(fr, fmaxf(ir, og));
    float ef = __expf((fr-mx)*inv_t);
    float ei = __expf((ir-mx)*inv_t);
    float eo = __expf((og-mx)*inv_t);
    float inv_s = 1.0f/(ef+ei+eo);
    float ft = ef*inv_s, it = ei*inv_s, ot = eo*inv_s;

    f32x2 cp = *(const f32x2*)(c_prev + 2*((size_t)b*1024 + h));
    f32x2 dp = *(const f32x2*)(d_prev + 2*((size_t)b*1024 + h));

    float r0 = (1.f-ft)*cp[0], r1 = (1.f-ft)*cp[1];
    float rm2 = r0*r0 + r1*r1;
    conv_acc += rm2 + 1e-8f;
    float rmag = sqrtf(rm2 + 1e-8f);
    float cm = __expf(0.66666667f * __logf(rmag));
    float rx = r0 + 1e-10f;
    float hr = fmaxf(sqrtf(rx*rx + r1*r1), 1e-30f);
    float invhr = cm / hr;
    float comp0 = fminf(fmaxf(rx*invhr, -10.f), 10.f);
    float comp1 = fminf(fmaxf(r1*invhr, -10.f), 10.f);

    float d0 = dp[0] + 0.01f*comp0;
    float d1 = dp[1] + 0.01f*comp1;
    float dmn = sqrtf(d0*d0 + d1*d1 + 1e-8f);
    if (dmn > 20.f){ float sc = 20.f/dmn; d0*=sc; d1*=sc; }

    float gt0 = ftanh(g0), gt1 = ftanh(g1);
    float cu0 = ft*cp[0] + it*gt0;
    float cu1 = ft*cp[1] + it*gt1;
    float th = theta[h];
    float sth, cth;
    __sincosf(th, &sth, &cth);
    float c0 = cth*cu0 - sth*cu1;
    float c1 = sth*cu0 + cth*cu1;
    float cs0 = ftanh(c0), cs1 = ftanh(c1);
    float hr0 = ot*cs0, hr1 = ot*cs1;

    float hx = hr0 + 1e-10f, dx = d0 + 1e-10f;
    float hh = sqrtf(hx*hx + hr1*hr1);
    float hd = sqrtf(dx*dx + d1*d1);
    float cosd = (hx*dx + hr1*d1) / fmaxf(hh*hd, 1e-30f);
    float G = 0.5f + 0.5f*cosd;
    float h0 = G*hr0, h1 = G*hr1;
    emer_acc += h0*h0 + h1*h1 + 1e-8f;

    h0 = (h0==h0)?h0:0.f;  h1 = (h1==h1)?h1:0.f;
    c0 = (c0==c0)?c0:0.f;  c1 = (c1==c1)?c1:0.f;
    d0 = (d0==d0)?d0:0.f;  d1 = (d1==d1)?d1:0.f;

    size_t oi = 2*((size_t)b*1024 + h);
    *(f32x2*)(Hout+oi) = f32x2{h0,h1};
    *(f32x2*)(Cout+oi) = f32x2{c0,c1};
    *(f32x2*)(Dout+oi) = f32x2{d0,d1};
  }

  #pragma unroll
  for (int off=32; off; off>>=1){
    conv_acc += __shfl_down(conv_acc, off);
    emer_acc += __shfl_down(emer_acc, off);
  }
  __shared__ float sred[8];
  int wv = tid>>6, ln = tid&63;
  if (ln==0){ sred[wv]=conv_acc; sred[4+wv]=emer_acc; }
  __syncthreads();
  if (tid==0){
    float cv = sred[0]+sred[1]+sred[2]+sred[3];
    float em = sred[4]+sred[5]+sred[6]+sred[7];
    float bm = cv/(cv+em+1e-8f);
    float bt = 0.99f*bp + 0.01f*bm;
    bt = (bt==bt)?bt:0.5f;
    Bout[b] = bt;
  }
}

extern "C" void kernel_launch(void* const* d_in, const int* in_sizes, int n_in,
                              void* d_out, int out_size, void* d_ws, size_t ws_size,
                              hipStream_t stream)
{
  const float* x_t    = (const float*)d_in[0];
  const float* h_prev = (const float*)d_in[1];
  const float* c_prev = (const float*)d_in[2];
  const float* d_prev = (const float*)d_in[3];
  const float* b_prev = (const float*)d_in[4];
  const float* Wf_w   = (const float*)d_in[5];
  const float* Wf_b   = (const float*)d_in[6];
  const float* Wi_w   = (const float*)d_in[7];
  const float* Wi_b   = (const float*)d_in[8];
  const float* Wo_w   = (const float*)d_in[9];
  const float* Wo_b   = (const float*)d_in[10];
  const float* Wc_w   = (const float*)d_in[11];
  const float* Wc_b   = (const float*)d_in[12];
  const float* Wr_w   = (const float*)d_in[13];
  const float* Wr_b   = (const float*)d_in[14];
  const float* theta  = (const float*)d_in[15];

  char* W = (char*)d_ws;
  // OFF0: rawfio f32 [4096][3072]; xc f32 [4096][2048] aliased (dead before fio GEMM)
  float* rawfio = (float*)W;
  float* xc     = (float*)W;
  // OFF1 = 50331648: Wr_hi(4M)|Wr_lo(4M)|x_lo(8M) transient, later raw_g bf16 [4096][2048]
  u16*   Wr_hi  = (u16*)(W + 50331648);
  u16*   Wr_lo  = (u16*)(W + 50331648 + 4194304);
  u16*   x_lo   = (u16*)(W + 50331648 + 8388608);
  u16*   raw_g  = (u16*)(W + 50331648);
  // OFF2 = 67108864: cA bf16 [4096][5120]
  u16*   cA     = (u16*)(W + 67108864);
  // OFF3 = 109051904: WD3 bf16 [3072][5120] (fio), then Wc bf16 [2048][5120] reuse
  u16*   WD     = (u16*)(W + 109051904);
  // OFF4 = 140509184: idx (4097 ints) then smap (4096 ints)
  int*   idx    = (int*)(W + 140509184);
  int*   smap   = (int*)(W + 140509184 + 16388);
  // OFF5 = 140546048: surf_cmp f32 [cap][2048]
  float* Scmp   = (float*)(W + 140546048);
  long long avail = (long long)ws_size - 140546048LL;
  int cap = (int)(avail > 0 ? avail / 8192 : 0);
  if (cap > 1024) cap = 1024;

  dim3 blk(256);

  // 1. x,h -> cA[:,0:3072] + x_lo
  cvt_xh<<<dim3(3,4096), blk, 0, stream>>>(x_t, h_prev, cA, x_lo);
  // 2. Wr -> hi/lo
  cvt_hilo<<<2048, blk, 0, stream>>>(Wr_w, Wr_hi, Wr_lo, 524288);
  // 3. GEMM1 (split 3-pass, gemm128 48-MFMA/phase): xc = x @ Wr^T + b
  gemm128<true,false><<<dim3(8,32), dim3(512), 0, stream>>>(
      cA, 5120, x_lo, 1024, Wr_hi, 1024, Wr_lo,
      Wr_b, xc, nullptr, 2048, 1024);
  // 4. flag low-temperature rows
  flag_rows<<<1, blk, 0, stream>>>(b_prev, idx, smap, cap);
  // 5. surfaced -> cA[:,3072:5120] (+ compact f32 for flagged rows)
  prep_surf<<<16384, blk, 0, stream>>>(xc, d_prev, smap, Scmp, cA, cap);
  // 6. Wf,Wi,Wo -> WD3
  cvt_hi<<<5120, blk, 0, stream>>>(Wf_w, WD, 1310720);
  cvt_hi<<<5120, blk, 0, stream>>>(Wi_w, WD + (size_t)1024*5120, 1310720);
  cvt_hi<<<5120, blk, 0, stream>>>(Wo_w, WD + (size_t)2048*5120, 1310720);
  // 7. f/i/o merged (8-phase 256x256, R5 known-good), 192 blocks
  gemm8p<4,false,3><<<dim3(12,16), dim3(512), 0, stream>>>(
      cA, 5120, WD, 5120, Wf_b, Wi_b, Wo_b, rawfio, nullptr, 3072, 5120);
  // 8. bias-init flagged rows, then split-K precise fixup (16-way)
  fix_init<<<4096, blk, 0, stream>>>(smap, idx, Wf_b, Wi_b, Wo_b, rawfio);
  gemm_fix_sk<<<dim3(24,8,FIX_KC), blk, 0, stream>>>(
      x_t, h_prev, Scmp, smap, Wf_w, Wi_w, Wo_w, idx, rawfio);
  // 9. Wc -> WD (reuse), g raw (gemm128 16-MFMA/phase, 256 blocks, bf16 out)
  cvt_hi<<<10240, blk, 0, stream>>>(Wc_w, WD, 2621440);
  gemm128<false,true><<<dim3(8,32), dim3(512), 0, stream>>>(
      cA, 5120, nullptr, 0, WD, 5120, nullptr,
      Wc_b, nullptr, raw_g, 2048, 5120);
  // 10. epilogue
  epilogue<<<4096, blk, 0, stream>>>(rawfio, raw_g, c_prev, d_prev, b_prev, theta, (float*)d_out);
}

// Round 8
// 497.829 us; speedup vs baseline: 1.2110x; 1.0554x over previous
//
#include <hip/hip_runtime.h>
#include <math.h>

typedef unsigned short u16;
typedef unsigned int u32;
typedef u16 u16x4 __attribute__((ext_vector_type(4)));
typedef float f32x2 __attribute__((ext_vector_type(2)));
typedef float f32x4 __attribute__((ext_vector_type(4)));
typedef __bf16 bf16x8 __attribute__((ext_vector_type(8)));

#define CAPF 256

__device__ __forceinline__ u16 f2bf(float f){
  u32 u = __builtin_bit_cast(u32, f);
  u32 r = u + 0x7FFFu + ((u >> 16) & 1u);
  return (u16)(r >> 16);
}
__device__ __forceinline__ float bf2f(u16 h){
  u32 u = ((u32)h) << 16;
  return __builtin_bit_cast(float, u);
}
__device__ __forceinline__ float ftanh(float x){
  float e = __expf(2.f*x);
  return 1.f - 2.f/(e+1.f);
}

typedef __attribute__((address_space(1))) const unsigned int gas_u32;
typedef __attribute__((address_space(3))) unsigned int las_u32;
__device__ __forceinline__ void gload_lds16(const void* g, void* l){
  __builtin_amdgcn_global_load_lds((gas_u32*)g, (las_u32*)l, 16, 0, 0);
}

// ---------------- prep0: fused cvt_xh + cvt_hilo(Wr) + zero(rawfix) + flag_rows ----------------
__global__ __launch_bounds__(256) void prep0(
    const float* __restrict__ x, const float* __restrict__ h,
    u16* __restrict__ cA, u16* __restrict__ xlo,
    const float* __restrict__ Wr, u16* __restrict__ Wr_hi, u16* __restrict__ Wr_lo,
    const float* __restrict__ bp, int* __restrict__ idx, int* __restrict__ smap,
    float* __restrict__ rawfix)
{
  const int bx = blockIdx.x, tid = threadIdx.x;
  if (bx < 12288){
    // cvt_xh: x,h -> cA[:,0:3072] bf16; x -> x_lo
    int b = bx / 3, cb = bx - b*3;
    int c0 = (cb*256 + tid)*4;
    f32x4 v;
    if (c0 < 1024) v = *(const f32x4*)(x + (size_t)b*1024 + c0);
    else           v = *(const f32x4*)(h + (size_t)b*2048 + (c0-1024));
    u16x4 hi4;
    #pragma unroll
    for (int j=0;j<4;++j) hi4[j]=f2bf(v[j]);
    *(u16x4*)(cA + (size_t)b*5120 + c0) = hi4;
    if (c0 < 1024){
      u16x4 lo4;
      #pragma unroll
      for (int j=0;j<4;++j) lo4[j]=f2bf(v[j]-bf2f(hi4[j]));
      *(u16x4*)(xlo + (size_t)b*1024 + c0) = lo4;
    }
  } else if (bx < 14336){
    // cvt_hilo Wr (524288 quads)
    int i = (bx-12288)*256 + tid;
    f32x4 v = *(const f32x4*)(Wr + (size_t)i*4);
    u16x4 oh, ol;
    #pragma unroll
    for (int j=0;j<4;++j){ u16 hh=f2bf(v[j]); oh[j]=hh; ol[j]=f2bf(v[j]-bf2f(hh)); }
    *(u16x4*)(Wr_hi + (size_t)i*4) = oh;
    *(u16x4*)(Wr_lo + (size_t)i*4) = ol;
  } else if (bx < 15104){
    // zero rawfix (CAPF*3072 f32 = 768 blocks x 256 x f32x4)
    int i = (bx-14336)*256 + tid;
    *(f32x4*)(rawfix + (size_t)i*4) = f32x4{0.f,0.f,0.f,0.f};
  } else {
    // flag low-temperature rows
    __shared__ int cnt;
    if (tid==0) cnt=0;
    __syncthreads();
    for (int i=tid; i<4096; i+=256){
      int p = -1;
      if (bp[i] < 0.04f){
        p = atomicAdd(&cnt,1);
        if (p < CAPF) idx[1+p]=i;
      }
      smap[i] = p;
    }
    __syncthreads();
    if (tid==0) idx[0] = min(cnt, CAPF);
  }
}

// ---------------- cvtW3: Wf,Wi,Wo f32 -> WD3 bf16 (single launch) ----------------
__global__ __launch_bounds__(256) void cvtW3(
    const float* __restrict__ W0, const float* __restrict__ W1, const float* __restrict__ W2,
    u16* __restrict__ out)
{
  int i = blockIdx.x*256 + threadIdx.x;        // over 3*1310720 quads
  int seg = i / 1310720;
  int w = i - seg*1310720;
  const float* src = (seg==0) ? W0 : (seg==1 ? W1 : W2);
  f32x4 v = *(const f32x4*)(src + (size_t)w*4);
  u16x4 o;
  #pragma unroll
  for (int j=0;j<4;++j) o[j]=f2bf(v[j]);
  *(u16x4*)(out + (size_t)seg*5242880 + (size_t)w*4) = o;
}

__global__ __launch_bounds__(256) void cvt_hi(const float* __restrict__ in, u16* __restrict__ out, int n4){
  int i = blockIdx.x*256 + threadIdx.x;
  if (i >= n4) return;
  f32x4 v = *(const f32x4*)(in + (size_t)i*4);
  u16x4 o;
  #pragma unroll
  for (int j=0;j<4;++j) o[j]=f2bf(v[j]);
  *(u16x4*)(out + (size_t)i*4) = o;
}

// surfaced via dot-product identity. bf16 into cA[:,3072:5120]; f32 compact for flagged rows.
__global__ __launch_bounds__(256) void prep_surf(const float* __restrict__ xc, const float* __restrict__ dp,
                                                 const int* __restrict__ smap, float* __restrict__ Scmp,
                                                 u16* __restrict__ cA){
  int i = blockIdx.x*256 + threadIdx.x;   // over 4096*1024
  int b = i >> 10, h = i & 1023;
  f32x2 z = *(const f32x2*)(xc + 2*(size_t)i);
  f32x2 d = *(const f32x2*)(dp + 2*(size_t)i);
  float zx = z[0] + 1e-10f, dx = d[0] + 1e-10f;
  float hz = sqrtf(zx*zx + z[1]*z[1]);
  float hd = sqrtf(dx*dx + d[1]*d[1]);
  float cosd = (zx*dx + z[1]*d[1]) / fmaxf(hz*hd, 1e-30f);
  float T = 0.5f + 0.5f*cosd;
  float dmag = sqrtf(d[0]*d[0] + d[1]*d[1] + 1e-8f);
  float dscale = sqrtf(fminf(fmaxf(dmag, 1e-6f), 20.0f));
  float s = T * dscale / (dmag + 1e-8f);
  float o0 = d[0]*s, o1 = d[1]*s;
  u32 pk = (u32)f2bf(o0) | ((u32)f2bf(o1) << 16);
  *(u32*)&cA[(size_t)b*5120 + 3072 + 2*h] = pk;
  int p = smap[b];
  if (p >= 0 && p < CAPF)
    *(f32x2*)(Scmp + ((size_t)p*1024 + h)*2) = f32x2{o0, o1};
}

// ============ 8-phase 256x256 GEMM — deep counted vmcnt(8) at every odd phase ============
#define LDA8(BUF,H,MH,J) (*(const bf16x8*)(sAc + ((BUF)*2+(H))*16384 + abase + (MH)*4096 + (J)*1024))
#define LDB8(BUF,H,N)    (*(const bf16x8*)(sBc + ((BUF)*2+(H))*BHTB + bbase + (N)*1024))
#define STG_A8(BUF,H,TT) { const u16* s_ = Ah + aS + (size_t)(TT)*64 + (H)*32; \
    gload_lds16(s_, dA + ((BUF)*2+(H))*8192); \
    gload_lds16(s_ + aS2, dA + ((BUF)*2+(H))*8192 + 4096); }
#define STG_B8(BUF,H,TT) { const u16* s_ = Bh + bS + (size_t)(TT)*64 + (H)*32; \
    gload_lds16(s_, dB + ((BUF)*2+(H))*(BHTB/2)); \
    gload_lds16(s_ + bS2, dB + ((BUF)*2+(H))*(BHTB/2) + 4096); }
#define PH8(BUF,H,MH,RB,STG,DOW) do{ \
    bf16x8 af0 = LDA8(BUF,H,MH,0), af1 = LDA8(BUF,H,MH,1), af2 = LDA8(BUF,H,MH,2), af3 = LDA8(BUF,H,MH,3); \
    if (RB){ _Pragma("unroll") for(int n_=0;n_<NR;++n_) bfr[n_] = LDB8(BUF,H,n_); } \
    STG; \
    asm volatile("" ::: "memory"); \
    __builtin_amdgcn_s_barrier(); \
    asm volatile("s_waitcnt lgkmcnt(0)" ::: "memory"); \
    __builtin_amdgcn_sched_barrier(0); \
    __builtin_amdgcn_s_setprio(1); \
    _Pragma("unroll") for(int n_=0;n_<NR;++n_){ \
      acc[(MH)*4+0][n_] = __builtin_amdgcn_mfma_f32_16x16x32_bf16(af0, bfr[n_], acc[(MH)*4+0][n_],0,0,0); \
      acc[(MH)*4+1][n_] = __builtin_amdgcn_mfma_f32_16x16x32_bf16(af1, bfr[n_], acc[(MH)*4+1][n_],0,0,0); \
      acc[(MH)*4+2][n_] = __builtin_amdgcn_mfma_f32_16x16x32_bf16(af2, bfr[n_], acc[(MH)*4+2][n_],0,0,0); \
      acc[(MH)*4+3][n_] = __builtin_amdgcn_mfma_f32_16x16x32_bf16(af3, bfr[n_], acc[(MH)*4+3][n_],0,0,0); } \
    __builtin_amdgcn_s_setprio(0); \
    if (DOW) { asm volatile("s_waitcnt vmcnt(%0)" :: "i"(VN) : "memory"); } \
    asm volatile("" ::: "memory"); \
    __builtin_amdgcn_s_barrier(); \
    __builtin_amdgcn_sched_barrier(0); \
  }while(0)

template<int NR, bool OUTBF, int NB>
__global__ __launch_bounds__(512) void gemm8p(
    const u16* __restrict__ Ah, int lda,
    const u16* __restrict__ Bh, int ldb,
    const float* __restrict__ bias0, const float* __restrict__ bias1, const float* __restrict__ bias2,
    float* __restrict__ Cf, u16* __restrict__ Cb, int ldc, int K)
{
  constexpr int BN   = NR*64;
  constexpr int BHTB = BN*64;
  constexpr int VN   = 8;              // 4 stages (8 loads) in flight; 5-phase slack
  __shared__ u16 sA[4*8192];
  __shared__ u16 sB[4*(NR*2048)];
  const char* sAc = (const char*)sA;
  const char* sBc = (const char*)sB;

  const int tid = threadIdx.x, lane = tid&63, w8 = tid>>6;
  const int wr = w8>>2, wc = w8&3;
  const int l16 = lane&15;

  const int gx = gridDim.x, nwg = gx*gridDim.y;
  const int lin = blockIdx.y*gx + blockIdx.x;
  const int sw = (lin&7)*(nwg>>3) + (lin>>3);
  const int m0 = (sw / gx)*256, n0 = (sw % gx)*BN;

  const int rowS  = tid>>2;
  const int ksS   = (tid&3) ^ ((tid>>3)&3);
  const size_t aS = (size_t)(m0 + rowS)*lda + ksS*8;
  const size_t aS2= (size_t)128*lda;
  const size_t bS = (size_t)(n0 + rowS)*ldb + ksS*8;
  const size_t bS2= (size_t)128*ldb;
  u16* dA = sA + w8*512;
  u16* dB = sB + w8*512;

  const int aslot = (lane>>4) ^ ((l16>>1)&3);
  const int abase = (wr*128 + l16)*64 + aslot*16;
  const int bbase = (wc*(NR*16) + l16)*64 + aslot*16;

  f32x4 acc[8][NR];
  #pragma unroll
  for (int a=0;a<8;++a)
    #pragma unroll
    for (int b=0;b<NR;++b) acc[a][b] = f32x4{0.f,0.f,0.f,0.f};
  bf16x8 bfr[NR];

  const int NT = K>>6, NITER = K>>7;

  STG_A8(0,0,0) STG_B8(0,0,0) STG_A8(0,1,0) STG_B8(0,1,0) STG_A8(1,0,1) STG_B8(1,0,1)
  asm volatile("s_waitcnt vmcnt(%0)" :: "i"(VN) : "memory");
  asm volatile("" ::: "memory");
  __builtin_amdgcn_s_barrier();
  __builtin_amdgcn_sched_barrier(0);

  for (int i=0; i<NITER; ++i){
    const int t1 = 2*i+1;
    const int ta = min(2*i+2, NT-1);
    const int tb = min(2*i+3, NT-1);
    PH8(0,0,0,true,  STG_A8(1,1,t1), false);
    PH8(0,0,1,false, STG_B8(1,1,t1), true);   // vmcnt(8): forces prev ph4/ph5 (A1,B1 of t0) landed
    PH8(0,1,0,true,  STG_A8(0,0,ta), false);
    PH8(0,1,1,false, STG_B8(0,0,ta), true);   // forces prev ph6/ph7 (A0,B0 of t1) landed
    PH8(1,0,0,true,  STG_A8(0,1,ta), false);
    PH8(1,0,1,false, STG_B8(0,1,ta), true);   // forces ph0/ph1 (A1,B1 of t1) landed
    PH8(1,1,0,true,  STG_A8(1,0,tb), false);
    PH8(1,1,1,false, STG_B8(1,0,tb), true);   // forces ph2/ph3 (A0,B0 of ta) landed
  }
  asm volatile("s_waitcnt vmcnt(0)" ::: "memory");

  #pragma unroll
  for (int mf=0; mf<8; ++mf){
    int grow = m0 + wr*128 + mf*16 + (lane>>4)*4;
    #pragma unroll
    for (int n=0; n<NR; ++n){
      int gcol = n0 + wc*(NR*16) + n*16 + l16;
      float bb;
      if constexpr(NB==3) bb = (gcol<1024) ? bias0[gcol] : ((gcol<2048) ? bias1[gcol-1024] : bias2[gcol-2048]);
      else bb = bias0[gcol];
      #pragma unroll
      for (int r2=0;r2<4;++r2){
        float v = acc[mf][n][r2] + bb;
        if constexpr(OUTBF) Cb[(size_t)(grow+r2)*ldc + gcol] = f2bf(v);
        else                Cf[(size_t)(grow+r2)*ldc + gcol] = v;
      }
    }
  }
}

// ============ gemm128: BM=128 BN=256 BK=32, BUFS-deep ring, 1 phase/tile ============
#define STG128(USRC, BW) do{ int u_=(USRC)<NT?(USRC):NT-1; \
    { const u16* s_=Ah+aS+(size_t)u_*32; gload_lds16(s_, sA+(BW)*4096+ldsb); } \
    { const u16* s_=Bh+bS+(size_t)u_*32; gload_lds16(s_, sB+(BW)*8192+ldsb); \
      gload_lds16(s_+bS2, sB+(BW)*8192+4096+ldsb); } \
    if constexpr(SPLIT){ \
      const u16* s2_=Al+aSl+(size_t)u_*32; gload_lds16(s2_, sAl+(BW)*4096+ldsb); \
      const u16* s3_=Bl+bS+(size_t)u_*32;  gload_lds16(s3_, sBl+(BW)*8192+ldsb); \
      gload_lds16(s3_+bS2, sBl+(BW)*8192+4096+ldsb); } \
  }while(0)

template<bool SPLIT, bool OUTBF, int BUFS>
__global__ __launch_bounds__(512) void gemm128(
    const u16* __restrict__ Ah, int lda,
    const u16* __restrict__ Al, int ldal,
    const u16* __restrict__ Bh, int ldb,
    const u16* __restrict__ Bl,
    const float* __restrict__ bias0,
    float* __restrict__ Cf, u16* __restrict__ Cb, int ldc, int K)
{
  constexpr int LPS = SPLIT ? 6 : 3;
  constexpr int VN  = (BUFS-2)*LPS;    // leave BUFS-2 newest stages outstanding
  constexpr int PRE = BUFS-1;
  __shared__ u16 sA [BUFS*4096];
  __shared__ u16 sB [BUFS*8192];
  __shared__ u16 sAl[SPLIT?BUFS*4096:8];
  __shared__ u16 sBl[SPLIT?BUFS*8192:8];

  const int tid=threadIdx.x, lane=tid&63, w8=tid>>6;
  const int wr=w8>>2, wc=w8&3, l16=lane&15;

  const int gx=gridDim.x, nwg=gx*gridDim.y;
  const int lin=blockIdx.y*gx+blockIdx.x;
  const int sw=(lin&7)*(nwg>>3)+(lin>>3);
  const int m0=(sw/gx)*128, n0=(sw%gx)*256;

  const int rowS=tid>>2;
  const int ksS=(tid&3)^((tid>>3)&3);
  const size_t aS =(size_t)(m0+rowS)*lda  + ksS*8;
  const size_t aSl=(size_t)(m0+rowS)*(size_t)ldal + ksS*8;
  const size_t bS =(size_t)(n0+rowS)*ldb  + ksS*8;
  const size_t bS2=(size_t)128*ldb;
  const int ldsb = w8*512;

  const int aslot=(lane>>4)^((l16>>1)&3);
  const int abase=(wr*64+l16)*64 + aslot*16;
  const int bbase=(wc*64+l16)*64 + aslot*16;

  f32x4 acc[4][4];
  #pragma unroll
  for (int a=0;a<4;++a)
    #pragma unroll
    for (int b=0;b<4;++b) acc[a][b] = f32x4{0.f,0.f,0.f,0.f};

  const int NT = K>>5;

  #pragma unroll
  for (int u=0; u<PRE; ++u){ STG128(u,u); }
  asm volatile("s_waitcnt vmcnt(%0)" :: "i"(VN) : "memory");
  asm volatile("" ::: "memory");
  __builtin_amdgcn_s_barrier();
  __builtin_amdgcn_sched_barrier(0);

  int bufR = 0;
  for (int t=0; t<NT; ++t){
    int bufW = (bufR==0) ? BUFS-1 : bufR-1;
    const char* sAc=(const char*)sA  + bufR*8192;
    const char* sBc=(const char*)sB  + bufR*16384;
    const char* sAlc=(const char*)sAl + bufR*8192;
    const char* sBlc=(const char*)sBl + bufR*16384;
    bf16x8 af[4], bf[4], afl[4], bfl[4];
    #pragma unroll
    for (int f=0; f<4; ++f){
      af[f] = *(const bf16x8*)(sAc + abase + f*1024);
      bf[f] = *(const bf16x8*)(sBc + bbase + f*1024);
      if constexpr(SPLIT){
        afl[f] = *(const bf16x8*)(sAlc + abase + f*1024);
        bfl[f] = *(const bf16x8*)(sBlc + bbase + f*1024);
      }
    }
    STG128(t+PRE, bufW);
    asm volatile("" ::: "memory");
    __builtin_amdgcn_s_barrier();
    asm volatile("s_waitcnt lgkmcnt(0)" ::: "memory");
    __builtin_amdgcn_sched_barrier(0);
    __builtin_amdgcn_s_setprio(1);
    #pragma unroll
    for (int mf=0; mf<4; ++mf){
      #pragma unroll
      for (int nf=0; nf<4; ++nf){
        acc[mf][nf] = __builtin_amdgcn_mfma_f32_16x16x32_bf16(af[mf], bf[nf], acc[mf][nf],0,0,0);
        if constexpr(SPLIT){
          acc[mf][nf] = __builtin_amdgcn_mfma_f32_16x16x32_bf16(afl[mf], bf[nf],  acc[mf][nf],0,0,0);
          acc[mf][nf] = __builtin_amdgcn_mfma_f32_16x16x32_bf16(af[mf],  bfl[nf], acc[mf][nf],0,0,0);
        }
      }
    }
    __builtin_amdgcn_s_setprio(0);
    asm volatile("s_waitcnt vmcnt(%0)" :: "i"(VN) : "memory");
    asm volatile("" ::: "memory");
    __builtin_amdgcn_s_barrier();
    __builtin_amdgcn_sched_barrier(0);
    bufR = (bufR+1==BUFS) ? 0 : bufR+1;
  }
  asm volatile("s_waitcnt vmcnt(0)" ::: "memory");

  #pragma unroll
  for (int mf=0; mf<4; ++mf){
    int grow = m0 + wr*64 + mf*16 + (lane>>4)*4;
    #pragma unroll
    for (int nf=0; nf<4; ++nf){
      int gcol = n0 + wc*64 + nf*16 + l16;
      float bb = bias0[gcol];
      #pragma unroll
      for (int r2=0;r2<4;++r2){
        float v = acc[mf][nf][r2] + bb;
        if constexpr(OUTBF) Cb[(size_t)(grow+r2)*ldc + gcol] = f2bf(v);
        else                Cf[(size_t)(grow+r2)*ldc + gcol] = v;
      }
    }
  }
}

// ---------------- fixup: precise 3-pass for flagged rows, SPLIT-K, compact output ----------------
#define LSTR 40
#define FIX_KC 16
#define FIX_KLEN 320
__global__ __launch_bounds__(256) void gemm_fix_sk(
    const float* __restrict__ Xs, const float* __restrict__ Hs,
    const float* __restrict__ Scmp, const int* __restrict__ smap,
    const float* __restrict__ W0, const float* __restrict__ W1, const float* __restrict__ W2,
    const int* __restrict__ cr, float* __restrict__ Cfix)
{
  const int count = cr[0];
  const int m0 = blockIdx.y * 128;
  if (m0 >= count) return;
  const int* rows = cr + 1;
  const int kbeg = blockIdx.z * FIX_KLEN;
  const int kend = kbeg + FIX_KLEN;

  __shared__ u16 sAh[128*LSTR];
  __shared__ u16 sAl[128*LSTR];
  __shared__ u16 sBh[128*LSTR];
  __shared__ u16 sBl[128*LSTR];

  const int tid = threadIdx.x;
  const int n0 = blockIdx.x * 128;
  int seg = n0 >> 10;
  const float* W = (seg==0) ? W0 : (seg==1 ? W1 : W2);
  int nw = n0 & 1023;

  const int wave = tid >> 6, lane = tid & 63;
  const int wm = wave >> 1, wn = wave & 1;
  const int l16 = lane & 15, lk8 = (lane >> 4) * 8;

  f32x4 acc[4][4];
  #pragma unroll
  for (int a=0;a<4;++a)
    #pragma unroll
    for (int b=0;b<4;++b) acc[a][b] = f32x4{0.f,0.f,0.f,0.f};

  for (int k0 = kbeg; k0 < kend; k0 += 32){
    #pragma unroll
    for (int i=0;i<4;++i){
      int flat = tid + i*256;
      int r  = flat >> 3;
      int c4 = flat & 7;
      int kk = k0 + c4*4;
      int mi = min(m0 + r, count-1);
      int mrow = rows[mi];
      const float* srcA;
      if (kk < 1024)      srcA = Xs + (size_t)mrow*1024 + kk;
      else if (kk < 3072) srcA = Hs + (size_t)mrow*2048 + (kk - 1024);
      else                srcA = Scmp + (size_t)smap[mrow]*2048 + (kk - 3072);
      f32x4 va = *(const f32x4*)srcA;
      f32x4 vb = *(const f32x4*)(W + (size_t)(nw + r)*5120 + kk);
      u16x4 ah, bh, al, bl;
      #pragma unroll
      for (int j=0;j<4;++j){
        u16 hA = f2bf(va[j]); ah[j] = hA; al[j] = f2bf(va[j] - bf2f(hA));
        u16 hB = f2bf(vb[j]); bh[j] = hB; bl[j] = f2bf(vb[j] - bf2f(hB));
      }
      int o = r*LSTR + c4*4;
      *(u16x4*)&sAh[o] = ah;
      *(u16x4*)&sBh[o] = bh;
      *(u16x4*)&sAl[o] = al;
      *(u16x4*)&sBl[o] = bl;
    }
    __syncthreads();
    bf16x8 fah[4], fbh[4], fal[4], fbl[4];
    #pragma unroll
    for (int f=0; f<4; ++f){
      int ra  = (wm*64 + f*16 + l16)*LSTR + lk8;
      int rb2 = (wn*64 + f*16 + l16)*LSTR + lk8;
      fah[f] = *(const bf16x8*)&sAh[ra];
      fbh[f] = *(const bf16x8*)&sBh[rb2];
      fal[f] = *(const bf16x8*)&sAl[ra];
      fbl[f] = *(const bf16x8*)&sBl[rb2];
    }
    #pragma unroll
    for (int fm=0; fm<4; ++fm){
      #pragma unroll
      for (int fn=0; fn<4; ++fn){
        acc[fm][fn] = __builtin_amdgcn_mfma_f32_16x16x32_bf16(fah[fm], fbh[fn], acc[fm][fn], 0,0,0);
        acc[fm][fn] = __builtin_amdgcn_mfma_f32_16x16x32_bf16(fal[fm], fbh[fn], acc[fm][fn], 0,0,0);
        acc[fm][fn] = __builtin_amdgcn_mfma_f32_16x16x32_bf16(fah[fm], fbl[fn], acc[fm][fn], 0,0,0);
      }
    }
    __syncthreads();
  }

  #pragma unroll
  for (int fm=0; fm<4; ++fm){
    int trow = wm*64 + fm*16 + (lane>>4)*4;
    #pragma unroll
    for (int fn=0; fn<4; ++fn){
      int lcol = wn*64 + fn*16 + l16;
      #pragma unroll
      for (int r2=0;r2<4;++r2){
        int mi = m0 + trow + r2;
        if (mi < count){
          atomicAdd(&Cfix[(size_t)mi*3072 + (n0 + lcol)], acc[fm][fn][r2]);
        }
      }
    }
  }
}

// ---------------- epilogue (flagged rows read compact rawfix + bias) ----------------
__global__ __launch_bounds__(256) void epilogue(
    const float* __restrict__ rawfio, const u16* __restrict__ rawg,
    const float* __restrict__ rawfix, const int* __restrict__ smap, const int* __restrict__ cr,
    const float* __restrict__ bf0, const float* __restrict__ bf1, const float* __restrict__ bf2,
    const float* __restrict__ c_prev, const float* __restrict__ d_prev,
    const float* __restrict__ b_prev, const float* __restrict__ theta,
    float* __restrict__ out)
{
  const int b = blockIdx.x;
  const int tid = threadIdx.x;
  float* Hout = out;
  float* Cout = out + (size_t)8388608;
  float* Dout = out + (size_t)16777216;
  float* Bout = out + (size_t)25165824;
  const float bp = b_prev[b];
  const float inv_t = 1.0f / (2.0f*bp + 1e-4f);
  float conv_acc = 0.f, emer_acc = 0.f;
  const size_t rb3 = (size_t)b*3072;
  const size_t rg = (size_t)b*2048;
  const int p = smap[b];
  const bool fx = (p >= 0 && p < cr[0]);
  const size_t rfx = (size_t)p*3072;

  #pragma unroll
  for (int j=0;j<4;++j){
    int h = tid + j*256;
    float fr, ir, og;
    if (fx){
      fr = rawfix[rfx + h]        + bf0[h];
      ir = rawfix[rfx + 1024 + h] + bf1[h];
      og = rawfix[rfx + 2048 + h] + bf2[h];
    } else {
      fr = rawfio[rb3 + h];
      ir = rawfio[rb3 + 1024 + h];
      og = rawfio[rb3 + 2048 + h];
    }
    float g0 = bf2f(rawg[rg + h]);
    float g1 = bf2f(rawg[rg + 1024 + h]);

    float mx = fmaxf(fr, fmaxf(ir, og));
    float ef = __expf((fr-mx)*inv_t);
    float ei = __expf((ir-mx)*inv_t);
    float eo = __expf((og-mx)*inv_t);
    float inv_s = 1.0f/(ef+ei+eo);
    float ft = ef*inv_s, it = ei*inv_s, ot = eo*inv_s;

    f32x2 cp = *(const f32x2*)(c_prev + 2*((size_t)b*1024 + h));
    f32x2 dp = *(const f32x2*)(d_prev + 2*((size_t)b*1024 + h));

    float r0 = (1.f-ft)*cp[0], r1 = (1.f-ft)*cp[1];
    float rm2 = r0*r0 + r1*r1;
    conv_acc += rm2 + 1e-8f;
    float rmag = sqrtf(rm2 + 1e-8f);
    float cm = __expf(0.66666667f * __logf(rmag));
    float rx = r0 + 1e-10f;
    float hr = fmaxf(sqrtf(rx*rx + r1*r1), 1e-30f);
    float invhr = cm / hr;
    float comp0 = fminf(fmaxf(rx*invhr, -10.f), 10.f);
    float comp1 = fminf(fmaxf(r1*invhr, -10.f), 10.f);

    float d0 = dp[0] + 0.01f*comp0;
    float d1 = dp[1] + 0.01f*comp1;
    float dmn = sqrtf(d0*d0 + d1*d1 + 1e-8f);
    if (dmn > 20.f){ float sc = 20.f/dmn; d0*=sc; d1*=sc; }

    float gt0 = ftanh(g0), gt1 = ftanh(g1);
    float cu0 = ft*cp[0] + it*gt0;
    float cu1 = ft*cp[1] + it*gt1;
    float th = theta[h];
    float sth, cth;
    __sincosf(th, &sth, &cth);
    float c0 = cth*cu0 - sth*cu1;
    float c1 = sth*cu0 + cth*cu1;
    float cs0 = ftanh(c0), cs1 = ftanh(c1);
    float hr0 = ot*cs0, hr1 = ot*cs1;

    float hx = hr0 + 1e-10f, dx = d0 + 1e-10f;
    float hh = sqrtf(hx*hx + hr1*hr1);
    float hd = sqrtf(dx*dx + d1*d1);
    float cosd = (hx*dx + hr1*d1) / fmaxf(hh*hd, 1e-30f);
    float G = 0.5f + 0.5f*cosd;
    float h0 = G*hr0, h1 = G*hr1;
    emer_acc += h0*h0 + h1*h1 + 1e-8f;

    h0 = (h0==h0)?h0:0.f;  h1 = (h1==h1)?h1:0.f;
    c0 = (c0==c0)?c0:0.f;  c1 = (c1==c1)?c1:0.f;
    d0 = (d0==d0)?d0:0.f;  d1 = (d1==d1)?d1:0.f;

    size_t oi = 2*((size_t)b*1024 + h);
    *(f32x2*)(Hout+oi) = f32x2{h0,h1};
    *(f32x2*)(Cout+oi) = f32x2{c0,c1};
    *(f32x2*)(Dout+oi) = f32x2{d0,d1};
  }

  #pragma unroll
  for (int off=32; off; off>>=1){
    conv_acc += __shfl_down(conv_acc, off);
    emer_acc += __shfl_down(emer_acc, off);
  }
  __shared__ float sred[8];
  int wv = tid>>6, ln = tid&63;
  if (ln==0){ sred[wv]=conv_acc; sred[4+wv]=emer_acc; }
  __syncthreads();
  if (tid==0){
    float cv = sred[0]+sred[1]+sred[2]+sred[3];
    float em = sred[4]+sred[5]+sred[6]+sred[7];
    float bm = cv/(cv+em+1e-8f);
    float bt = 0.99f*bp + 0.01f*bm;
    bt = (bt==bt)?bt:0.5f;
    Bout[b] = bt;
  }
}

extern "C" void kernel_launch(void* const* d_in, const int* in_sizes, int n_in,
                              void* d_out, int out_size, void* d_ws, size_t ws_size,
                              hipStream_t stream)
{
  const float* x_t    = (const float*)d_in[0];
  const float* h_prev = (const float*)d_in[1];
  const float* c_prev = (const float*)d_in[2];
  const float* d_prev = (const float*)d_in[3];
  const float* b_prev = (const float*)d_in[4];
  const float* Wf_w   = (const float*)d_in[5];
  const float* Wf_b   = (const float*)d_in[6];
  const float* Wi_w   = (const float*)d_in[7];
  const float* Wi_b   = (const float*)d_in[8];
  const float* Wo_w   = (const float*)d_in[9];
  const float* Wo_b   = (const float*)d_in[10];
  const float* Wc_w   = (const float*)d_in[11];
  const float* Wc_b   = (const float*)d_in[12];
  const float* Wr_w   = (const float*)d_in[13];
  const float* Wr_b   = (const float*)d_in[14];
  const float* theta  = (const float*)d_in[15];

  char* W = (char*)d_ws;
  // OFF0: rawfio f32 [4096][3072]; xc f32 [4096][2048] aliased (dead before fio GEMM)
  float* rawfio = (float*)W;
  float* xc     = (float*)W;
  // OFF1 = 50331648: Wr_hi(4M)|Wr_lo(4M)|x_lo(8M) transient, later raw_g bf16 [4096][2048]
  u16*   Wr_hi  = (u16*)(W + 50331648);
  u16*   Wr_lo  = (u16*)(W + 50331648 + 4194304);
  u16*   x_lo   = (u16*)(W + 50331648 + 8388608);
  u16*   raw_g  = (u16*)(W + 50331648);
  // OFF2 = 67108864: cA bf16 [4096][5120]
  u16*   cA     = (u16*)(W + 67108864);
  // OFF3 = 109051904: WD3 bf16 [3072][5120] (fio), then Wc bf16 [2048][5120] reuse
  u16*   WD     = (u16*)(W + 109051904);
  // OFF4 = 140509184: idx (4097 ints) then smap (4096 ints)
  int*   idx    = (int*)(W + 140509184);
  int*   smap   = (int*)(W + 140509184 + 16388);
  // OFF5 = 140546048: Scmp f32 [CAPF][2048] (2MB); OFF6: rawfix f32 [CAPF][3072] (3MB)
  float* Scmp   = (float*)(W + 140546048);
  float* rawfix = (float*)(W + 140546048 + (size_t)CAPF*2048*4);

  dim3 blk(256);

  // 1. fused: x/h cvt + Wr hi/lo + zero rawfix + flag rows
  prep0<<<15105, blk, 0, stream>>>(x_t, h_prev, cA, x_lo, Wr_w, Wr_hi, Wr_lo,
                                   b_prev, idx, smap, rawfix);
  // 2. GEMM1 (split 3-pass, gemm128 3-buf): xc = x @ Wr^T + b
  gemm128<true,false,3><<<dim3(8,32), dim3(512), 0, stream>>>(
      cA, 5120, x_lo, 1024, Wr_hi, 1024, Wr_lo,
      Wr_b, xc, nullptr, 2048, 1024);
  // 3. surfaced -> cA[:,3072:5120] (+ compact f32 for flagged rows)
  prep_surf<<<16384, blk, 0, stream>>>(xc, d_prev, smap, Scmp, cA);
  // 4. precise split-K fixup into compact rawfix (order-free wrt fio GEMM)
  gemm_fix_sk<<<dim3(24,8,FIX_KC), blk, 0, stream>>>(
      x_t, h_prev, Scmp, smap, Wf_w, Wi_w, Wo_w, idx, rawfix);
  // 5. Wf,Wi,Wo -> WD3 (one launch)
  cvtW3<<<15360, blk, 0, stream>>>(Wf_w, Wi_w, Wo_w, WD);
  // 6. f/i/o merged (8-phase 256x256, deep vmcnt(8)), 192 blocks
  gemm8p<4,false,3><<<dim3(12,16), dim3(512), 0, stream>>>(
      cA, 5120, WD, 5120, Wf_b, Wi_b, Wo_b, rawfio, nullptr, 3072, 5120);
  // 7. Wc -> WD (reuse), g raw (gemm128 5-buf deep, 256 blocks, bf16 out)
  cvt_hi<<<10240, blk, 0, stream>>>(Wc_w, WD, 2621440);
  gemm128<false,true,5><<<dim3(8,32), dim3(512), 0, stream>>>(
      cA, 5120, nullptr, 0, WD, 5120, nullptr,
      Wc_b, nullptr, raw_g, 2048, 5120);
  // 8. epilogue
  epilogue<<<4096, blk, 0, stream>>>(rawfio, raw_g, rawfix, smap, idx,
                                     Wf_b, Wi_b, Wo_b,
                                     c_prev, d_prev, b_prev, theta, (float*)d_out);
}

// Round 9
// 496.488 us; speedup vs baseline: 1.2143x; 1.0027x over previous
//
#include <hip/hip_runtime.h>
#include <math.h>

typedef unsigned short u16;
typedef unsigned int u32;
typedef u16 u16x4 __attribute__((ext_vector_type(4)));
typedef float f32x2 __attribute__((ext_vector_type(2)));
typedef float f32x4 __attribute__((ext_vector_type(4)));
typedef __bf16 bf16x8 __attribute__((ext_vector_type(8)));

#define CAPF 256

__device__ __forceinline__ u16 f2bf(float f){
  u32 u = __builtin_bit_cast(u32, f);
  u32 r = u + 0x7FFFu + ((u >> 16) & 1u);
  return (u16)(r >> 16);
}
__device__ __forceinline__ float bf2f(u16 h){
  u32 u = ((u32)h) << 16;
  return __builtin_bit_cast(float, u);
}
__device__ __forceinline__ float ftanh(float x){
  float e = __expf(2.f*x);
  return 1.f - 2.f/(e+1.f);
}

typedef __attribute__((address_space(1))) const unsigned int gas_u32;
typedef __attribute__((address_space(3))) unsigned int las_u32;
__device__ __forceinline__ void gload_lds16(const void* g, void* l){
  __builtin_amdgcn_global_load_lds((gas_u32*)g, (las_u32*)l, 16, 0, 0);
}

// ---------------- prep0: fused cvt_xh + cvt_hilo(Wr) + zero(rawfix) + flag_rows ----------------
__global__ __launch_bounds__(256) void prep0(
    const float* __restrict__ x, const float* __restrict__ h,
    u16* __restrict__ cA, u16* __restrict__ xlo,
    const float* __restrict__ Wr, u16* __restrict__ Wr_hi, u16* __restrict__ Wr_lo,
    const float* __restrict__ bp, int* __restrict__ idx, int* __restrict__ smap,
    float* __restrict__ rawfix)
{
  const int bx = blockIdx.x, tid = threadIdx.x;
  if (bx < 12288){
    int b = bx / 3, cb = bx - b*3;
    int c0 = (cb*256 + tid)*4;
    f32x4 v;
    if (c0 < 1024) v = *(const f32x4*)(x + (size_t)b*1024 + c0);
    else           v = *(const f32x4*)(h + (size_t)b*2048 + (c0-1024));
    u16x4 hi4;
    #pragma unroll
    for (int j=0;j<4;++j) hi4[j]=f2bf(v[j]);
    *(u16x4*)(cA + (size_t)b*5120 + c0) = hi4;
    if (c0 < 1024){
      u16x4 lo4;
      #pragma unroll
      for (int j=0;j<4;++j) lo4[j]=f2bf(v[j]-bf2f(hi4[j]));
      *(u16x4*)(xlo + (size_t)b*1024 + c0) = lo4;
    }
  } else if (bx < 14336){
    int i = (bx-12288)*256 + tid;
    f32x4 v = *(const f32x4*)(Wr + (size_t)i*4);
    u16x4 oh, ol;
    #pragma unroll
    for (int j=0;j<4;++j){ u16 hh=f2bf(v[j]); oh[j]=hh; ol[j]=f2bf(v[j]-bf2f(hh)); }
    *(u16x4*)(Wr_hi + (size_t)i*4) = oh;
    *(u16x4*)(Wr_lo + (size_t)i*4) = ol;
  } else if (bx < 15104){
    int i = (bx-14336)*256 + tid;
    *(f32x4*)(rawfix + (size_t)i*4) = f32x4{0.f,0.f,0.f,0.f};
  } else {
    __shared__ int cnt;
    if (tid==0) cnt=0;
    __syncthreads();
    for (int i=tid; i<4096; i+=256){
      int p = -1;
      if (bp[i] < 0.04f){
        p = atomicAdd(&cnt,1);
        if (p < CAPF) idx[1+p]=i;
      }
      smap[i] = p;
    }
    __syncthreads();
    if (tid==0) idx[0] = min(cnt, CAPF);
  }
}

// ---------------- cvtW3: Wf,Wi,Wo f32 -> WD3 bf16 (single launch) ----------------
__global__ __launch_bounds__(256) void cvtW3(
    const float* __restrict__ W0, const float* __restrict__ W1, const float* __restrict__ W2,
    u16* __restrict__ out)
{
  int i = blockIdx.x*256 + threadIdx.x;
  int seg = i / 1310720;
  int w = i - seg*1310720;
  const float* src = (seg==0) ? W0 : (seg==1 ? W1 : W2);
  f32x4 v = *(const f32x4*)(src + (size_t)w*4);
  u16x4 o;
  #pragma unroll
  for (int j=0;j<4;++j) o[j]=f2bf(v[j]);
  *(u16x4*)(out + (size_t)seg*5242880 + (size_t)w*4) = o;
}

__global__ __launch_bounds__(256) void cvt_hi(const float* __restrict__ in, u16* __restrict__ out, int n4){
  int i = blockIdx.x*256 + threadIdx.x;
  if (i >= n4) return;
  f32x4 v = *(const f32x4*)(in + (size_t)i*4);
  u16x4 o;
  #pragma unroll
  for (int j=0;j<4;++j) o[j]=f2bf(v[j]);
  *(u16x4*)(out + (size_t)i*4) = o;
}

// surfaced via dot-product identity. bf16 into cA[:,3072:5120]; f32 compact for flagged rows.
__global__ __launch_bounds__(256) void prep_surf(const float* __restrict__ xc, const float* __restrict__ dp,
                                                 const int* __restrict__ smap, float* __restrict__ Scmp,
                                                 u16* __restrict__ cA){
  int i = blockIdx.x*256 + threadIdx.x;
  int b = i >> 10, h = i & 1023;
  f32x2 z = *(const f32x2*)(xc + 2*(size_t)i);
  f32x2 d = *(const f32x2*)(dp + 2*(size_t)i);
  float zx = z[0] + 1e-10f, dx = d[0] + 1e-10f;
  float hz = sqrtf(zx*zx + z[1]*z[1]);
  float hd = sqrtf(dx*dx + d[1]*d[1]);
  float cosd = (zx*dx + z[1]*d[1]) / fmaxf(hz*hd, 1e-30f);
  float T = 0.5f + 0.5f*cosd;
  float dmag = sqrtf(d[0]*d[0] + d[1]*d[1] + 1e-8f);
  float dscale = sqrtf(fminf(fmaxf(dmag, 1e-6f), 20.0f));
  float s = T * dscale / (dmag + 1e-8f);
  float o0 = d[0]*s, o1 = d[1]*s;
  u32 pk = (u32)f2bf(o0) | ((u32)f2bf(o1) << 16);
  *(u32*)&cA[(size_t)b*5120 + 3072 + 2*h] = pk;
  int p = smap[b];
  if (p >= 0 && p < CAPF)
    *(f32x2*)(Scmp + ((size_t)p*1024 + h)*2) = f32x2{o0, o1};
}

// ============ 8-phase 256x256 GEMM — compiler-scheduled lgkm (no all-reads pin) ============
#define LDA8(BUF,H,MH,J) (*(const bf16x8*)(sAc + ((BUF)*2+(H))*16384 + abase + (MH)*4096 + (J)*1024))
#define LDB8(BUF,H,N)    (*(const bf16x8*)(sBc + ((BUF)*2+(H))*BHTB + bbase + (N)*1024))
#define STG_A8(BUF,H,TT) { const u16* s_ = Ah + aS + (size_t)(TT)*64 + (H)*32; \
    gload_lds16(s_, dA + ((BUF)*2+(H))*8192); \
    gload_lds16(s_ + aS2, dA + ((BUF)*2+(H))*8192 + 4096); }
#define STG_B8(BUF,H,TT) { const u16* s_ = Bh + bS + (size_t)(TT)*64 + (H)*32; \
    gload_lds16(s_, dB + ((BUF)*2+(H))*(BHTB/2)); \
    gload_lds16(s_ + bS2, dB + ((BUF)*2+(H))*(BHTB/2) + 4096); }
#define PH8(BUF,H,MH,RB,STG,DOW) do{ \
    bf16x8 af0 = LDA8(BUF,H,MH,0), af1 = LDA8(BUF,H,MH,1), af2 = LDA8(BUF,H,MH,2), af3 = LDA8(BUF,H,MH,3); \
    if (RB){ _Pragma("unroll") for(int n_=0;n_<NR;++n_) bfr[n_] = LDB8(BUF,H,n_); } \
    STG; \
    asm volatile("" ::: "memory"); \
    __builtin_amdgcn_s_barrier(); \
    __builtin_amdgcn_s_setprio(1); \
    _Pragma("unroll") for(int n_=0;n_<NR;++n_){ \
      acc[(MH)*4+0][n_] = __builtin_amdgcn_mfma_f32_16x16x32_bf16(af0, bfr[n_], acc[(MH)*4+0][n_],0,0,0); \
      acc[(MH)*4+1][n_] = __builtin_amdgcn_mfma_f32_16x16x32_bf16(af1, bfr[n_], acc[(MH)*4+1][n_],0,0,0); \
      acc[(MH)*4+2][n_] = __builtin_amdgcn_mfma_f32_16x16x32_bf16(af2, bfr[n_], acc[(MH)*4+2][n_],0,0,0); \
      acc[(MH)*4+3][n_] = __builtin_amdgcn_mfma_f32_16x16x32_bf16(af3, bfr[n_], acc[(MH)*4+3][n_],0,0,0); } \
    __builtin_amdgcn_s_setprio(0); \
    if (DOW) { asm volatile("s_waitcnt vmcnt(%0)" :: "i"(VN) : "memory"); } \
    asm volatile("" ::: "memory"); \
    __builtin_amdgcn_s_barrier(); \
  }while(0)

template<int NR, bool OUTBF, int NB>
__global__ __launch_bounds__(512) void gemm8p(
    const u16* __restrict__ Ah, int lda,
    const u16* __restrict__ Bh, int ldb,
    const float* __restrict__ bias0, const float* __restrict__ bias1, const float* __restrict__ bias2,
    float* __restrict__ Cf, u16* __restrict__ Cb, int ldc, int K)
{
  constexpr int BN   = NR*64;
  constexpr int BHTB = BN*64;
  constexpr int VN   = 8;
  __shared__ u16 sA[4*8192];
  __shared__ u16 sB[4*(NR*2048)];
  const char* sAc = (const char*)sA;
  const char* sBc = (const char*)sB;

  const int tid = threadIdx.x, lane = tid&63, w8 = tid>>6;
  const int wr = w8>>2, wc = w8&3;
  const int l16 = lane&15;

  const int gx = gridDim.x, nwg = gx*gridDim.y;
  const int lin = blockIdx.y*gx + blockIdx.x;
  const int sw = (lin&7)*(nwg>>3) + (lin>>3);
  const int m0 = (sw / gx)*256, n0 = (sw % gx)*BN;

  const int rowS  = tid>>2;
  const int ksS   = (tid&3) ^ ((tid>>3)&3);
  const size_t aS = (size_t)(m0 + rowS)*lda + ksS*8;
  const size_t aS2= (size_t)128*lda;
  const size_t bS = (size_t)(n0 + rowS)*ldb + ksS*8;
  const size_t bS2= (size_t)128*ldb;
  u16* dA = sA + w8*512;
  u16* dB = sB + w8*512;

  const int aslot = (lane>>4) ^ ((l16>>1)&3);
  const int abase = (wr*128 + l16)*64 + aslot*16;
  const int bbase = (wc*(NR*16) + l16)*64 + aslot*16;

  f32x4 acc[8][NR];
  #pragma unroll
  for (int a=0;a<8;++a)
    #pragma unroll
    for (int b=0;b<NR;++b) acc[a][b] = f32x4{0.f,0.f,0.f,0.f};
  bf16x8 bfr[NR];

  const int NT = K>>6, NITER = K>>7;

  STG_A8(0,0,0) STG_B8(0,0,0) STG_A8(0,1,0) STG_B8(0,1,0) STG_A8(1,0,1) STG_B8(1,0,1)
  asm volatile("s_waitcnt vmcnt(%0)" :: "i"(VN) : "memory");
  asm volatile("" ::: "memory");
  __builtin_amdgcn_s_barrier();

  for (int i=0; i<NITER; ++i){
    const int t1 = 2*i+1;
    const int ta = min(2*i+2, NT-1);
    const int tb = min(2*i+3, NT-1);
    PH8(0,0,0,true,  STG_A8(1,1,t1), false);
    PH8(0,0,1,false, STG_B8(1,1,t1), true);
    PH8(0,1,0,true,  STG_A8(0,0,ta), false);
    PH8(0,1,1,false, STG_B8(0,0,ta), true);
    PH8(1,0,0,true,  STG_A8(0,1,ta), false);
    PH8(1,0,1,false, STG_B8(0,1,ta), true);
    PH8(1,1,0,true,  STG_A8(1,0,tb), false);
    PH8(1,1,1,false, STG_B8(1,0,tb), true);
  }
  asm volatile("s_waitcnt vmcnt(0)" ::: "memory");

  #pragma unroll
  for (int mf=0; mf<8; ++mf){
    int grow = m0 + wr*128 + mf*16 + (lane>>4)*4;
    #pragma unroll
    for (int n=0; n<NR; ++n){
      int gcol = n0 + wc*(NR*16) + n*16 + l16;
      float bb;
      if constexpr(NB==3) bb = (gcol<1024) ? bias0[gcol] : ((gcol<2048) ? bias1[gcol-1024] : bias2[gcol-2048]);
      else bb = bias0[gcol];
      #pragma unroll
      for (int r2=0;r2<4;++r2){
        float v = acc[mf][n][r2] + bb;
        if constexpr(OUTBF) Cb[(size_t)(grow+r2)*ldc + gcol] = f2bf(v);
        else                Cf[(size_t)(grow+r2)*ldc + gcol] = v;
      }
    }
  }
}

// ============ gemm128: BM=128 BN=256 BK=32, BUFS-deep ring, compiler-scheduled lgkm ============
#define STG128(USRC, BW) do{ int u_=(USRC)<NT?(USRC):NT-1; \
    { const u16* s_=Ah+aS+(size_t)u_*32; gload_lds16(s_, sA+(BW)*4096+ldsb); } \
    { const u16* s_=Bh+bS+(size_t)u_*32; gload_lds16(s_, sB+(BW)*8192+ldsb); \
      gload_lds16(s_+bS2, sB+(BW)*8192+4096+ldsb); } \
    if constexpr(SPLIT){ \
      const u16* s2_=Al+aSl+(size_t)u_*32; gload_lds16(s2_, sAl+(BW)*4096+ldsb); \
      const u16* s3_=Bl+bS+(size_t)u_*32;  gload_lds16(s3_, sBl+(BW)*8192+ldsb); \
      gload_lds16(s3_+bS2, sBl+(BW)*8192+4096+ldsb); } \
  }while(0)

template<bool SPLIT, bool OUTBF, int BUFS>
__global__ __launch_bounds__(512) void gemm128(
    const u16* __restrict__ Ah, int lda,
    const u16* __restrict__ Al, int ldal,
    const u16* __restrict__ Bh, int ldb,
    const u16* __restrict__ Bl,
    const float* __restrict__ bias0,
    float* __restrict__ Cf, u16* __restrict__ Cb, int ldc, int K)
{
  constexpr int LPS = SPLIT ? 6 : 3;
  constexpr int VN  = (BUFS-2)*LPS;
  constexpr int PRE = BUFS-1;
  __shared__ u16 sA [BUFS*4096];
  __shared__ u16 sB [BUFS*8192];
  __shared__ u16 sAl[SPLIT?BUFS*4096:8];
  __shared__ u16 sBl[SPLIT?BUFS*8192:8];

  const int tid=threadIdx.x, lane=tid&63, w8=tid>>6;
  const int wr=w8>>2, wc=w8&3, l16=lane&15;

  const int gx=gridDim.x, nwg=gx*gridDim.y;
  const int lin=blockIdx.y*gx+blockIdx.x;
  const int sw=(lin&7)*(nwg>>3)+(lin>>3);
  const int m0=(sw/gx)*128, n0=(sw%gx)*256;

  const int rowS=tid>>2;
  const int ksS=(tid&3)^((tid>>3)&3);
  const size_t aS =(size_t)(m0+rowS)*lda  + ksS*8;
  const size_t aSl=(size_t)(m0+rowS)*(size_t)ldal + ksS*8;
  const size_t bS =(size_t)(n0+rowS)*ldb  + ksS*8;
  const size_t bS2=(size_t)128*ldb;
  const int ldsb = w8*512;

  const int aslot=(lane>>4)^((l16>>1)&3);
  const int abase=(wr*64+l16)*64 + aslot*16;
  const int bbase=(wc*64+l16)*64 + aslot*16;

  f32x4 acc[4][4];
  #pragma unroll
  for (int a=0;a<4;++a)
    #pragma unroll
    for (int b=0;b<4;++b) acc[a][b] = f32x4{0.f,0.f,0.f,0.f};

  const int NT = K>>5;

  #pragma unroll
  for (int u=0; u<PRE; ++u){ STG128(u,u); }
  asm volatile("s_waitcnt vmcnt(%0)" :: "i"(VN) : "memory");
  asm volatile("" ::: "memory");
  __builtin_amdgcn_s_barrier();

  int bufR = 0;
  for (int t=0; t<NT; ++t){
    int bufW = (bufR==0) ? BUFS-1 : bufR-1;
    const char* sAc=(const char*)sA  + bufR*8192;
    const char* sBc=(const char*)sB  + bufR*16384;
    const char* sAlc=(const char*)sAl + bufR*8192;
    const char* sBlc=(const char*)sBl + bufR*16384;
    bf16x8 af[4], bf[4], afl[4], bfl[4];
    #pragma unroll
    for (int f=0; f<4; ++f){
      af[f] = *(const bf16x8*)(sAc + abase + f*1024);
      bf[f] = *(const bf16x8*)(sBc + bbase + f*1024);
      if constexpr(SPLIT){
        afl[f] = *(const bf16x8*)(sAlc + abase + f*1024);
        bfl[f] = *(const bf16x8*)(sBlc + bbase + f*1024);
      }
    }
    STG128(t+PRE, bufW);
    asm volatile("" ::: "memory");
    __builtin_amdgcn_s_barrier();
    __builtin_amdgcn_s_setprio(1);
    #pragma unroll
    for (int mf=0; mf<4; ++mf){
      #pragma unroll
      for (int nf=0; nf<4; ++nf){
        acc[mf][nf] = __builtin_amdgcn_mfma_f32_16x16x32_bf16(af[mf], bf[nf], acc[mf][nf],0,0,0);
        if constexpr(SPLIT){
          acc[mf][nf] = __builtin_amdgcn_mfma_f32_16x16x32_bf16(afl[mf], bf[nf],  acc[mf][nf],0,0,0);
          acc[mf][nf] = __builtin_amdgcn_mfma_f32_16x16x32_bf16(af[mf],  bfl[nf], acc[mf][nf],0,0,0);
        }
      }
    }
    __builtin_amdgcn_s_setprio(0);
    asm volatile("s_waitcnt vmcnt(%0)" :: "i"(VN) : "memory");
    asm volatile("" ::: "memory");
    __builtin_amdgcn_s_barrier();
    bufR = (bufR+1==BUFS) ? 0 : bufR+1;
  }
  asm volatile("s_waitcnt vmcnt(0)" ::: "memory");

  #pragma unroll
  for (int mf=0; mf<4; ++mf){
    int grow = m0 + wr*64 + mf*16 + (lane>>4)*4;
    #pragma unroll
    for (int nf=0; nf<4; ++nf){
      int gcol = n0 + wc*64 + nf*16 + l16;
      float bb = bias0[gcol];
      #pragma unroll
      for (int r2=0;r2<4;++r2){
        float v = acc[mf][nf][r2] + bb;
        if constexpr(OUTBF) Cb[(size_t)(grow+r2)*ldc + gcol] = f2bf(v);
        else                Cf[(size_t)(grow+r2)*ldc + gcol] = v;
      }
    }
  }
}

// ---------------- fixup: precise 3-pass for flagged rows, SPLIT-K, compact output ----------------
#define LSTR 40
#define FIX_KC 16
#define FIX_KLEN 320
__global__ __launch_bounds__(256) void gemm_fix_sk(
    const float* __restrict__ Xs, const float* __restrict__ Hs,
    const float* __restrict__ Scmp, const int* __restrict__ smap,
    const float* __restrict__ W0, const float* __restrict__ W1, const float* __restrict__ W2,
    const int* __restrict__ cr, float* __restrict__ Cfix)
{
  const int count = cr[0];
  const int m0 = blockIdx.y * 128;
  if (m0 >= count) return;
  const int* rows = cr + 1;
  const int kbeg = blockIdx.z * FIX_KLEN;
  const int kend = kbeg + FIX_KLEN;

  __shared__ u16 sAh[128*LSTR];
  __shared__ u16 sAl[128*LSTR];
  __shared__ u16 sBh[128*LSTR];
  __shared__ u16 sBl[128*LSTR];

  const int tid = threadIdx.x;
  const int n0 = blockIdx.x * 128;
  int seg = n0 >> 10;
  const float* W = (seg==0) ? W0 : (seg==1 ? W1 : W2);
  int nw = n0 & 1023;

  const int wave = tid >> 6, lane = tid & 63;
  const int wm = wave >> 1, wn = wave & 1;
  const int l16 = lane & 15, lk8 = (lane >> 4) * 8;

  f32x4 acc[4][4];
  #pragma unroll
  for (int a=0;a<4;++a)
    #pragma unroll
    for (int b=0;b<4;++b) acc[a][b] = f32x4{0.f,0.f,0.f,0.f};

  for (int k0 = kbeg; k0 < kend; k0 += 32){
    #pragma unroll
    for (int i=0;i<4;++i){
      int flat = tid + i*256;
      int r  = flat >> 3;
      int c4 = flat & 7;
      int kk = k0 + c4*4;
      int mi = min(m0 + r, count-1);
      int mrow = rows[mi];
      const float* srcA;
      if (kk < 1024)      srcA = Xs + (size_t)mrow*1024 + kk;
      else if (kk < 3072) srcA = Hs + (size_t)mrow*2048 + (kk - 1024);
      else                srcA = Scmp + (size_t)smap[mrow]*2048 + (kk - 3072);
      f32x4 va = *(const f32x4*)srcA;
      f32x4 vb = *(const f32x4*)(W + (size_t)(nw + r)*5120 + kk);
      u16x4 ah, bh, al, bl;
      #pragma unroll
      for (int j=0;j<4;++j){
        u16 hA = f2bf(va[j]); ah[j] = hA; al[j] = f2bf(va[j] - bf2f(hA));
        u16 hB = f2bf(vb[j]); bh[j] = hB; bl[j] = f2bf(vb[j] - bf2f(hB));
      }
      int o = r*LSTR + c4*4;
      *(u16x4*)&sAh[o] = ah;
      *(u16x4*)&sBh[o] = bh;
      *(u16x4*)&sAl[o] = al;
      *(u16x4*)&sBl[o] = bl;
    }
    __syncthreads();
    bf16x8 fah[4], fbh[4], fal[4], fbl[4];
    #pragma unroll
    for (int f=0; f<4; ++f){
      int ra  = (wm*64 + f*16 + l16)*LSTR + lk8;
      int rb2 = (wn*64 + f*16 + l16)*LSTR + lk8;
      fah[f] = *(const bf16x8*)&sAh[ra];
      fbh[f] = *(const bf16x8*)&sBh[rb2];
      fal[f] = *(const bf16x8*)&sAl[ra];
      fbl[f] = *(const bf16x8*)&sBl[rb2];
    }
    #pragma unroll
    for (int fm=0; fm<4; ++fm){
      #pragma unroll
      for (int fn=0; fn<4; ++fn){
        acc[fm][fn] = __builtin_amdgcn_mfma_f32_16x16x32_bf16(fah[fm], fbh[fn], acc[fm][fn], 0,0,0);
        acc[fm][fn] = __builtin_amdgcn_mfma_f32_16x16x32_bf16(fal[fm], fbh[fn], acc[fm][fn], 0,0,0);
        acc[fm][fn] = __builtin_amdgcn_mfma_f32_16x16x32_bf16(fah[fm], fbl[fn], acc[fm][fn], 0,0,0);
      }
    }
    __syncthreads();
  }

  #pragma unroll
  for (int fm=0; fm<4; ++fm){
    int trow = wm*64 + fm*16 + (lane>>4)*4;
    #pragma unroll
    for (int fn=0; fn<4; ++fn){
      int lcol = wn*64 + fn*16 + l16;
      #pragma unroll
      for (int r2=0;r2<4;++r2){
        int mi = m0 + trow + r2;
        if (mi < count){
          atomicAdd(&Cfix[(size_t)mi*3072 + (n0 + lcol)], acc[fm][fn][r2]);
        }
      }
    }
  }
}

// ---------------- epilogue (flagged rows read compact rawfix + bias) ----------------
__global__ __launch_bounds__(256) void epilogue(
    const float* __restrict__ rawfio, const u16* __restrict__ rawg,
    const float* __restrict__ rawfix, const int* __restrict__ smap, const int* __restrict__ cr,
    const float* __restrict__ bf0, const float* __restrict__ bf1, const float* __restrict__ bf2,
    const float* __restrict__ c_prev, const float* __restrict__ d_prev,
    const float* __restrict__ b_prev, const float* __restrict__ theta,
    float* __restrict__ out)
{
  const int b = blockIdx.x;
  const int tid = threadIdx.x;
  float* Hout = out;
  float* Cout = out + (size_t)8388608;
  float* Dout = out + (size_t)16777216;
  float* Bout = out + (size_t)25165824;
  const float bp = b_prev[b];
  const float inv_t = 1.0f / (2.0f*bp + 1e-4f);
  float conv_acc = 0.f, emer_acc = 0.f;
  const size_t rb3 = (size_t)b*3072;
  const size_t rg = (size_t)b*2048;
  const int p = smap[b];
  const bool fx = (p >= 0 && p < cr[0]);
  const size_t rfx = (size_t)p*3072;

  #pragma unroll
  for (int j=0;j<4;++j){
    int h = tid + j*256;
    float fr, ir, og;
    if (fx){
      fr = rawfix[rfx + h]        + bf0[h];
      ir = rawfix[rfx + 1024 + h] + bf1[h];
      og = rawfix[rfx + 2048 + h] + bf2[h];
    } else {
      fr = rawfio[rb3 + h];
      ir = rawfio[rb3 + 1024 + h];
      og = rawfio[rb3 + 2048 + h];
    }
    float g0 = bf2f(rawg[rg + h]);
    float g1 = bf2f(rawg[rg + 1024 + h]);

    float mx = fmaxf(fr, fmaxf(ir, og));
    float ef = __expf((fr-mx)*inv_t);
    float ei = __expf((ir-mx)*inv_t);
    float eo = __expf((og-mx)*inv_t);
    float inv_s = 1.0f/(ef+ei+eo);
    float ft = ef*inv_s, it = ei*inv_s, ot = eo*inv_s;

    f32x2 cp = *(const f32x2*)(c_prev + 2*((size_t)b*1024 + h));
    f32x2 dp = *(const f32x2*)(d_prev + 2*((size_t)b*1024 + h));

    float r0 = (1.f-ft)*cp[0], r1 = (1.f-ft)*cp[1];
    float rm2 = r0*r0 + r1*r1;
    conv_acc += rm2 + 1e-8f;
    float rmag = sqrtf(rm2 + 1e-8f);
    float cm = __expf(0.66666667f * __logf(rmag));
    float rx = r0 + 1e-10f;
    float hr = fmaxf(sqrtf(rx*rx + r1*r1), 1e-30f);
    float invhr = cm / hr;
    float comp0 = fminf(fmaxf(rx*invhr, -10.f), 10.f);
    float comp1 = fminf(fmaxf(r1*invhr, -10.f), 10.f);

    float d0 = dp[0] + 0.01f*comp0;
    float d1 = dp[1] + 0.01f*comp1;
    float dmn = sqrtf(d0*d0 + d1*d1 + 1e-8f);
    if (dmn > 20.f){ float sc = 20.f/dmn; d0*=sc; d1*=sc; }

    float gt0 = ftanh(g0), gt1 = ftanh(g1);
    float cu0 = ft*cp[0] + it*gt0;
    float cu1 = ft*cp[1] + it*gt1;
    float th = theta[h];
    float sth, cth;
    __sincosf(th, &sth, &cth);
    float c0 = cth*cu0 - sth*cu1;
    float c1 = sth*cu0 + cth*cu1;
    float cs0 = ftanh(c0), cs1 = ftanh(c1);
    float hr0 = ot*cs0, hr1 = ot*cs1;

    float hx = hr0 + 1e-10f, dx = d0 + 1e-10f;
    float hh = sqrtf(hx*hx + hr1*hr1);
    float hd = sqrtf(dx*dx + d1*d1);
    float cosd = (hx*dx + hr1*d1) / fmaxf(hh*hd, 1e-30f);
    float G = 0.5f + 0.5f*cosd;
    float h0 = G*hr0, h1 = G*hr1;
    emer_acc += h0*h0 + h1*h1 + 1e-8f;

    h0 = (h0==h0)?h0:0.f;  h1 = (h1==h1)?h1:0.f;
    c0 = (c0==c0)?c0:0.f;  c1 = (c1==c1)?c1:0.f;
    d0 = (d0==d0)?d0:0.f;  d1 = (d1==d1)?d1:0.f;

    size_t oi = 2*((size_t)b*1024 + h);
    *(f32x2*)(Hout+oi) = f32x2{h0,h1};
    *(f32x2*)(Cout+oi) = f32x2{c0,c1};
    *(f32x2*)(Dout+oi) = f32x2{d0,d1};
  }

  #pragma unroll
  for (int off=32; off; off>>=1){
    conv_acc += __shfl_down(conv_acc, off);
    emer_acc += __shfl_down(emer_acc, off);
  }
  __shared__ float sred[8];
  int wv = tid>>6, ln = tid&63;
  if (ln==0){ sred[wv]=conv_acc; sred[4+wv]=emer_acc; }
  __syncthreads();
  if (tid==0){
    float cv = sred[0]+sred[1]+sred[2]+sred[3];
    float em = sred[4]+sred[5]+sred[6]+sred[7];
    float bm = cv/(cv+em+1e-8f);
    float bt = 0.99f*bp + 0.01f*bm;
    bt = (bt==bt)?bt:0.5f;
    Bout[b] = bt;
  }
}

extern "C" void kernel_launch(void* const* d_in, const int* in_sizes, int n_in,
                              void* d_out, int out_size, void* d_ws, size_t ws_size,
                              hipStream_t stream)
{
  const float* x_t    = (const float*)d_in[0];
  const float* h_prev = (const float*)d_in[1];
  const float* c_prev = (const float*)d_in[2];
  const float* d_prev = (const float*)d_in[3];
  const float* b_prev = (const float*)d_in[4];
  const float* Wf_w   = (const float*)d_in[5];
  const float* Wf_b   = (const float*)d_in[6];
  const float* Wi_w   = (const float*)d_in[7];
  const float* Wi_b   = (const float*)d_in[8];
  const float* Wo_w   = (const float*)d_in[9];
  const float* Wo_b   = (const float*)d_in[10];
  const float* Wc_w   = (const float*)d_in[11];
  const float* Wc_b   = (const float*)d_in[12];
  const float* Wr_w   = (const float*)d_in[13];
  const float* Wr_b   = (const float*)d_in[14];
  const float* theta  = (const float*)d_in[15];

  char* W = (char*)d_ws;
  float* rawfio = (float*)W;
  float* xc     = (float*)W;
  u16*   Wr_hi  = (u16*)(W + 50331648);
  u16*   Wr_lo  = (u16*)(W + 50331648 + 4194304);
  u16*   x_lo   = (u16*)(W + 50331648 + 8388608);
  u16*   raw_g  = (u16*)(W + 50331648);
  u16*   cA     = (u16*)(W + 67108864);
  u16*   WD     = (u16*)(W + 109051904);
  int*   idx    = (int*)(W + 140509184);
  int*   smap   = (int*)(W + 140509184 + 16388);
  float* Scmp   = (float*)(W + 140546048);
  float* rawfix = (float*)(W + 140546048 + (size_t)CAPF*2048*4);

  dim3 blk(256);

  prep0<<<15105, blk, 0, stream>>>(x_t, h_prev, cA, x_lo, Wr_w, Wr_hi, Wr_lo,
                                   b_prev, idx, smap, rawfix);
  gemm128<true,false,3><<<dim3(8,32), dim3(512), 0, stream>>>(
      cA, 5120, x_lo, 1024, Wr_hi, 1024, Wr_lo,
      Wr_b, xc, nullptr, 2048, 1024);
  prep_surf<<<16384, blk, 0, stream>>>(xc, d_prev, smap, Scmp, cA);
  gemm_fix_sk<<<dim3(24,8,FIX_KC), blk, 0, stream>>>(
      x_t, h_prev, Scmp, smap, Wf_w, Wi_w, Wo_w, idx, rawfix);
  cvtW3<<<15360, blk, 0, stream>>>(Wf_w, Wi_w, Wo_w, WD);
  gemm8p<4,false,3><<<dim3(12,16), dim3(512), 0, stream>>>(
      cA, 5120, WD, 5120, Wf_b, Wi_b, Wo_b, rawfio, nullptr, 3072, 5120);
  cvt_hi<<<10240, blk, 0, stream>>>(Wc_w, WD, 2621440);
  gemm128<false,true,5><<<dim3(8,32), dim3(512), 0, stream>>>(
      cA, 5120, nullptr, 0, WD, 5120, nullptr,
      Wc_b, nullptr, raw_g, 2048, 5120);
  epilogue<<<4096, blk, 0, stream>>>(rawfio, raw_g, rawfix, smap, idx,
                                     Wf_b, Wi_b, Wo_b,
                                     c_prev, d_prev, b_prev, theta, (float*)d_out);
}

// Round 10
// 491.912 us; speedup vs baseline: 1.2256x; 1.0093x over previous
//
#include <hip/hip_runtime.h>
#include <math.h>

typedef unsigned short u16;
typedef unsigned int u32;
typedef u16 u16x4 __attribute__((ext_vector_type(4)));
typedef float f32x2 __attribute__((ext_vector_type(2)));
typedef float f32x4 __attribute__((ext_vector_type(4)));
typedef __bf16 bf16x8 __attribute__((ext_vector_type(8)));

#define CAPF 256

__device__ __forceinline__ u16 f2bf(float f){
  u32 u = __builtin_bit_cast(u32, f);
  u32 r = u + 0x7FFFu + ((u >> 16) & 1u);
  return (u16)(r >> 16);
}
__device__ __forceinline__ float bf2f(u16 h){
  u32 u = ((u32)h) << 16;
  return __builtin_bit_cast(float, u);
}
__device__ __forceinline__ float ftanh(float x){
  float e = __expf(2.f*x);
  return 1.f - 2.f/(e+1.f);
}

typedef __attribute__((address_space(1))) const unsigned int gas_u32;
typedef __attribute__((address_space(3))) unsigned int las_u32;
__device__ __forceinline__ void gload_lds16(const void* g, void* l){
  __builtin_amdgcn_global_load_lds((gas_u32*)g, (las_u32*)l, 16, 0, 0);
}

// ---------------- prep0: fused cvt_xh + cvt_hilo(Wr) + zero(rawfix) + flag_rows ----------------
__global__ __launch_bounds__(256) void prep0(
    const float* __restrict__ x, const float* __restrict__ h,
    u16* __restrict__ cA, u16* __restrict__ xlo,
    const float* __restrict__ Wr, u16* __restrict__ Wr_hi, u16* __restrict__ Wr_lo,
    const float* __restrict__ bp, int* __restrict__ idx, int* __restrict__ smap,
    float* __restrict__ rawfix)
{
  const int bx = blockIdx.x, tid = threadIdx.x;
  if (bx < 12288){
    int b = bx / 3, cb = bx - b*3;
    int c0 = (cb*256 + tid)*4;
    f32x4 v;
    if (c0 < 1024) v = *(const f32x4*)(x + (size_t)b*1024 + c0);
    else           v = *(const f32x4*)(h + (size_t)b*2048 + (c0-1024));
    u16x4 hi4;
    #pragma unroll
    for (int j=0;j<4;++j) hi4[j]=f2bf(v[j]);
    *(u16x4*)(cA + (size_t)b*5120 + c0) = hi4;
    if (c0 < 1024){
      u16x4 lo4;
      #pragma unroll
      for (int j=0;j<4;++j) lo4[j]=f2bf(v[j]-bf2f(hi4[j]));
      *(u16x4*)(xlo + (size_t)b*1024 + c0) = lo4;
    }
  } else if (bx < 14336){
    int i = (bx-12288)*256 + tid;
    f32x4 v = *(const f32x4*)(Wr + (size_t)i*4);
    u16x4 oh, ol;
    #pragma unroll
    for (int j=0;j<4;++j){ u16 hh=f2bf(v[j]); oh[j]=hh; ol[j]=f2bf(v[j]-bf2f(hh)); }
    *(u16x4*)(Wr_hi + (size_t)i*4) = oh;
    *(u16x4*)(Wr_lo + (size_t)i*4) = ol;
  } else if (bx < 15104){
    int i = (bx-14336)*256 + tid;
    *(f32x4*)(rawfix + (size_t)i*4) = f32x4{0.f,0.f,0.f,0.f};
  } else {
    __shared__ int cnt;
    if (tid==0) cnt=0;
    __syncthreads();
    for (int i=tid; i<4096; i+=256){
      int p = -1;
      if (bp[i] < 0.04f){
        p = atomicAdd(&cnt,1);
        if (p < CAPF) idx[1+p]=i;
      }
      smap[i] = p;
    }
    __syncthreads();
    if (tid==0) idx[0] = min(cnt, CAPF);
  }
}

// ---------------- cvtW3: Wf,Wi,Wo f32 -> WD3 bf16 (single launch) ----------------
__global__ __launch_bounds__(256) void cvtW3(
    const float* __restrict__ W0, const float* __restrict__ W1, const float* __restrict__ W2,
    u16* __restrict__ out)
{
  int i = blockIdx.x*256 + threadIdx.x;
  int seg = i / 1310720;
  int w = i - seg*1310720;
  const float* src = (seg==0) ? W0 : (seg==1 ? W1 : W2);
  f32x4 v = *(const f32x4*)(src + (size_t)w*4);
  u16x4 o;
  #pragma unroll
  for (int j=0;j<4;++j) o[j]=f2bf(v[j]);
  *(u16x4*)(out + (size_t)seg*5242880 + (size_t)w*4) = o;
}

__global__ __launch_bounds__(256) void cvt_hi(const float* __restrict__ in, u16* __restrict__ out, int n4){
  int i = blockIdx.x*256 + threadIdx.x;
  if (i >= n4) return;
  f32x4 v = *(const f32x4*)(in + (size_t)i*4);
  u16x4 o;
  #pragma unroll
  for (int j=0;j<4;++j) o[j]=f2bf(v[j]);
  *(u16x4*)(out + (size_t)i*4) = o;
}

// surfaced via dot-product identity. bf16 into cA[:,3072:5120]; f32 compact for flagged rows.
__global__ __launch_bounds__(256) void prep_surf(const float* __restrict__ xc, const float* __restrict__ dp,
                                                 const int* __restrict__ smap, float* __restrict__ Scmp,
                                                 u16* __restrict__ cA){
  int i = blockIdx.x*256 + threadIdx.x;
  int b = i >> 10, h = i & 1023;
  f32x2 z = *(const f32x2*)(xc + 2*(size_t)i);
  f32x2 d = *(const f32x2*)(dp + 2*(size_t)i);
  float zx = z[0] + 1e-10f, dx = d[0] + 1e-10f;
  float hz = sqrtf(zx*zx + z[1]*z[1]);
  float hd = sqrtf(dx*dx + d[1]*d[1]);
  float cosd = (zx*dx + z[1]*d[1]) / fmaxf(hz*hd, 1e-30f);
  float T = 0.5f + 0.5f*cosd;
  float dmag = sqrtf(d[0]*d[0] + d[1]*d[1] + 1e-8f);
  float dscale = sqrtf(fminf(fmaxf(dmag, 1e-6f), 20.0f));
  float s = T * dscale / (dmag + 1e-8f);
  float o0 = d[0]*s, o1 = d[1]*s;
  u32 pk = (u32)f2bf(o0) | ((u32)f2bf(o1) << 16);
  *(u32*)&cA[(size_t)b*5120 + 3072 + 2*h] = pk;
  int p = smap[b];
  if (p >= 0 && p < CAPF)
    *(f32x2*)(Scmp + ((size_t)p*1024 + h)*2) = f32x2{o0, o1};
}

// ============ 8-phase 256-row GEMM (NR=3 -> BN=192 exact-fill; NR=4 -> BN=256) ============
// B half-tiles staged as 256 rows always (top 64 rows unused for NR=3) so the
// vmcnt ledger and LDS layout are identical for all NR.
#define LDA8(BUF,H,MH,J) (*(const bf16x8*)(sAc + ((BUF)*2+(H))*16384 + abase + (MH)*4096 + (J)*1024))
#define LDB8(BUF,H,N)    (*(const bf16x8*)(sBc + ((BUF)*2+(H))*16384 + bbase + (N)*1024))
#define STG_A8(BUF,H,TT) { const u16* s_ = Ah + aS + (size_t)(TT)*64 + (H)*32; \
    gload_lds16(s_, dA + ((BUF)*2+(H))*8192); \
    gload_lds16(s_ + aS2, dA + ((BUF)*2+(H))*8192 + 4096); }
#define STG_B8(BUF,H,TT) { const u16* s_ = Bh + bS + (size_t)(TT)*64 + (H)*32; \
    gload_lds16(s_, dB + ((BUF)*2+(H))*8192); \
    gload_lds16(s_ + bS2, dB + ((BUF)*2+(H))*8192 + 4096); }
#define PH8(BUF,H,MH,RB,STG,DOW) do{ \
    bf16x8 af0 = LDA8(BUF,H,MH,0), af1 = LDA8(BUF,H,MH,1), af2 = LDA8(BUF,H,MH,2), af3 = LDA8(BUF,H,MH,3); \
    if (RB){ _Pragma("unroll") for(int n_=0;n_<NR;++n_) bfr[n_] = LDB8(BUF,H,n_); } \
    STG; \
    asm volatile("" ::: "memory"); \
    __builtin_amdgcn_s_barrier(); \
    __builtin_amdgcn_s_setprio(1); \
    _Pragma("unroll") for(int n_=0;n_<NR;++n_){ \
      acc[(MH)*4+0][n_] = __builtin_amdgcn_mfma_f32_16x16x32_bf16(af0, bfr[n_], acc[(MH)*4+0][n_],0,0,0); \
      acc[(MH)*4+1][n_] = __builtin_amdgcn_mfma_f32_16x16x32_bf16(af1, bfr[n_], acc[(MH)*4+1][n_],0,0,0); \
      acc[(MH)*4+2][n_] = __builtin_amdgcn_mfma_f32_16x16x32_bf16(af2, bfr[n_], acc[(MH)*4+2][n_],0,0,0); \
      acc[(MH)*4+3][n_] = __builtin_amdgcn_mfma_f32_16x16x32_bf16(af3, bfr[n_], acc[(MH)*4+3][n_],0,0,0); } \
    __builtin_amdgcn_s_setprio(0); \
    if (DOW) { asm volatile("s_waitcnt vmcnt(%0)" :: "i"(VN) : "memory"); } \
    asm volatile("" ::: "memory"); \
    __builtin_amdgcn_s_barrier(); \
  }while(0)

template<int NR, bool OUTBF, int NB>
__global__ __launch_bounds__(512) void gemm8p(
    const u16* __restrict__ Ah, int lda,
    const u16* __restrict__ Bh, int ldb,
    const float* __restrict__ bias0, const float* __restrict__ bias1, const float* __restrict__ bias2,
    float* __restrict__ Cf, u16* __restrict__ Cb, int ldc, int K)
{
  constexpr int BN   = NR*64;
  constexpr int VN   = 8;
  __shared__ u16 sA[4*8192];
  __shared__ u16 sB[4*8192];
  const char* sAc = (const char*)sA;
  const char* sBc = (const char*)sB;

  const int tid = threadIdx.x, lane = tid&63, w8 = tid>>6;
  const int wr = w8>>2, wc = w8&3;
  const int l16 = lane&15;

  const int gx = gridDim.x, nwg = gx*gridDim.y;
  const int lin = blockIdx.y*gx + blockIdx.x;
  const int sw = (lin&7)*(nwg>>3) + (lin>>3);
  const int m0 = (sw / gx)*256, n0 = (sw % gx)*BN;

  const int rowS  = tid>>2;
  const int ksS   = (tid&3) ^ ((tid>>3)&3);
  const size_t aS = (size_t)(m0 + rowS)*lda + ksS*8;
  const size_t aS2= (size_t)128*lda;
  const size_t bS = (size_t)(n0 + rowS)*ldb + ksS*8;
  const size_t bS2= (size_t)128*ldb;
  u16* dA = sA + w8*512;
  u16* dB = sB + w8*512;

  const int aslot = (lane>>4) ^ ((l16>>1)&3);
  const int abase = (wr*128 + l16)*64 + aslot*16;
  const int bbase = (wc*(NR*16) + l16)*64 + aslot*16;

  f32x4 acc[8][NR];
  #pragma unroll
  for (int a=0;a<8;++a)
    #pragma unroll
    for (int b=0;b<NR;++b) acc[a][b] = f32x4{0.f,0.f,0.f,0.f};
  bf16x8 bfr[NR];

  const int NT = K>>6, NITER = K>>7;

  STG_A8(0,0,0) STG_B8(0,0,0) STG_A8(0,1,0) STG_B8(0,1,0) STG_A8(1,0,1) STG_B8(1,0,1)
  asm volatile("s_waitcnt vmcnt(%0)" :: "i"(VN) : "memory");
  asm volatile("" ::: "memory");
  __builtin_amdgcn_s_barrier();

  for (int i=0; i<NITER; ++i){
    const int t1 = 2*i+1;
    const int ta = min(2*i+2, NT-1);
    const int tb = min(2*i+3, NT-1);
    PH8(0,0,0,true,  STG_A8(1,1,t1), false);
    PH8(0,0,1,false, STG_B8(1,1,t1), true);
    PH8(0,1,0,true,  STG_A8(0,0,ta), false);
    PH8(0,1,1,false, STG_B8(0,0,ta), true);
    PH8(1,0,0,true,  STG_A8(0,1,ta), false);
    PH8(1,0,1,false, STG_B8(0,1,ta), true);
    PH8(1,1,0,true,  STG_A8(1,0,tb), false);
    PH8(1,1,1,false, STG_B8(1,0,tb), true);
  }
  asm volatile("s_waitcnt vmcnt(0)" ::: "memory");

  #pragma unroll
  for (int mf=0; mf<8; ++mf){
    int grow = m0 + wr*128 + mf*16 + (lane>>4)*4;
    #pragma unroll
    for (int n=0; n<NR; ++n){
      int gcol = n0 + wc*(NR*16) + n*16 + l16;
      float bb;
      if constexpr(NB==3) bb = (gcol<1024) ? bias0[gcol] : ((gcol<2048) ? bias1[gcol-1024] : bias2[gcol-2048]);
      else bb = bias0[gcol];
      #pragma unroll
      for (int r2=0;r2<4;++r2){
        float v = acc[mf][n][r2] + bb;
        if constexpr(OUTBF) Cb[(size_t)(grow+r2)*ldc + gcol] = f2bf(v);
        else                Cf[(size_t)(grow+r2)*ldc + gcol] = v;
      }
    }
  }
}

// ============ gemm128: BM=128 BN=256 BK=32, BUFS-deep ring, compiler-scheduled lgkm ============
#define STG128(USRC, BW) do{ int u_=(USRC)<NT?(USRC):NT-1; \
    { const u16* s_=Ah+aS+(size_t)u_*32; gload_lds16(s_, sA+(BW)*4096+ldsb); } \
    { const u16* s_=Bh+bS+(size_t)u_*32; gload_lds16(s_, sB+(BW)*8192+ldsb); \
      gload_lds16(s_+bS2, sB+(BW)*8192+4096+ldsb); } \
    if constexpr(SPLIT){ \
      const u16* s2_=Al+aSl+(size_t)u_*32; gload_lds16(s2_, sAl+(BW)*4096+ldsb); \
      const u16* s3_=Bl+bS+(size_t)u_*32;  gload_lds16(s3_, sBl+(BW)*8192+ldsb); \
      gload_lds16(s3_+bS2, sBl+(BW)*8192+4096+ldsb); } \
  }while(0)

template<bool SPLIT, bool OUTBF, int BUFS>
__global__ __launch_bounds__(512) void gemm128(
    const u16* __restrict__ Ah, int lda,
    const u16* __restrict__ Al, int ldal,
    const u16* __restrict__ Bh, int ldb,
    const u16* __restrict__ Bl,
    const float* __restrict__ bias0,
    float* __restrict__ Cf, u16* __restrict__ Cb, int ldc, int K)
{
  constexpr int LPS = SPLIT ? 6 : 3;
  constexpr int VN  = (BUFS-2)*LPS;
  constexpr int PRE = BUFS-1;
  __shared__ u16 sA [BUFS*4096];
  __shared__ u16 sB [BUFS*8192];
  __shared__ u16 sAl[SPLIT?BUFS*4096:8];
  __shared__ u16 sBl[SPLIT?BUFS*8192:8];

  const int tid=threadIdx.x, lane=tid&63, w8=tid>>6;
  const int wr=w8>>2, wc=w8&3, l16=lane&15;

  const int gx=gridDim.x, nwg=gx*gridDim.y;
  const int lin=blockIdx.y*gx+blockIdx.x;
  const int sw=(lin&7)*(nwg>>3)+(lin>>3);
  const int m0=(sw/gx)*128, n0=(sw%gx)*256;

  const int rowS=tid>>2;
  const int ksS=(tid&3)^((tid>>3)&3);
  const size_t aS =(size_t)(m0+rowS)*lda  + ksS*8;
  const size_t aSl=(size_t)(m0+rowS)*(size_t)ldal + ksS*8;
  const size_t bS =(size_t)(n0+rowS)*ldb  + ksS*8;
  const size_t bS2=(size_t)128*ldb;
  const int ldsb = w8*512;

  const int aslot=(lane>>4)^((l16>>1)&3);
  const int abase=(wr*64+l16)*64 + aslot*16;
  const int bbase=(wc*64+l16)*64 + aslot*16;

  f32x4 acc[4][4];
  #pragma unroll
  for (int a=0;a<4;++a)
    #pragma unroll
    for (int b=0;b<4;++b) acc[a][b] = f32x4{0.f,0.f,0.f,0.f};

  const int NT = K>>5;

  #pragma unroll
  for (int u=0; u<PRE; ++u){ STG128(u,u); }
  asm volatile("s_waitcnt vmcnt(%0)" :: "i"(VN) : "memory");
  asm volatile("" ::: "memory");
  __builtin_amdgcn_s_barrier();

  int bufR = 0;
  for (int t=0; t<NT; ++t){
    int bufW = (bufR==0) ? BUFS-1 : bufR-1;
    const char* sAc=(const char*)sA  + bufR*8192;
    const char* sBc=(const char*)sB  + bufR*16384;
    const char* sAlc=(const char*)sAl + bufR*8192;
    const char* sBlc=(const char*)sBl + bufR*16384;
    bf16x8 af[4], bf[4], afl[4], bfl[4];
    #pragma unroll
    for (int f=0; f<4; ++f){
      af[f] = *(const bf16x8*)(sAc + abase + f*1024);
      bf[f] = *(const bf16x8*)(sBc + bbase + f*1024);
      if constexpr(SPLIT){
        afl[f] = *(const bf16x8*)(sAlc + abase + f*1024);
        bfl[f] = *(const bf16x8*)(sBlc + bbase + f*1024);
      }
    }
    STG128(t+PRE, bufW);
    asm volatile("" ::: "memory");
    __builtin_amdgcn_s_barrier();
    __builtin_amdgcn_s_setprio(1);
    #pragma unroll
    for (int mf=0; mf<4; ++mf){
      #pragma unroll
      for (int nf=0; nf<4; ++nf){
        acc[mf][nf] = __builtin_amdgcn_mfma_f32_16x16x32_bf16(af[mf], bf[nf], acc[mf][nf],0,0,0);
        if constexpr(SPLIT){
          acc[mf][nf] = __builtin_amdgcn_mfma_f32_16x16x32_bf16(afl[mf], bf[nf],  acc[mf][nf],0,0,0);
          acc[mf][nf] = __builtin_amdgcn_mfma_f32_16x16x32_bf16(af[mf],  bfl[nf], acc[mf][nf],0,0,0);
        }
      }
    }
    __builtin_amdgcn_s_setprio(0);
    asm volatile("s_waitcnt vmcnt(%0)" :: "i"(VN) : "memory");
    asm volatile("" ::: "memory");
    __builtin_amdgcn_s_barrier();
    bufR = (bufR+1==BUFS) ? 0 : bufR+1;
  }
  asm volatile("s_waitcnt vmcnt(0)" ::: "memory");

  #pragma unroll
  for (int mf=0; mf<4; ++mf){
    int grow = m0 + wr*64 + mf*16 + (lane>>4)*4;
    #pragma unroll
    for (int nf=0; nf<4; ++nf){
      int gcol = n0 + wc*64 + nf*16 + l16;
      float bb = bias0[gcol];
      #pragma unroll
      for (int r2=0;r2<4;++r2){
        float v = acc[mf][nf][r2] + bb;
        if constexpr(OUTBF) Cb[(size_t)(grow+r2)*ldc + gcol] = f2bf(v);
        else                Cf[(size_t)(grow+r2)*ldc + gcol] = v;
      }
    }
  }
}

// ---------------- fixup: precise 3-pass for flagged rows, SPLIT-K, compact output ----------------
#define LSTR 40
#define FIX_KC 16
#define FIX_KLEN 320
__global__ __launch_bounds__(256) void gemm_fix_sk(
    const float* __restrict__ Xs, const float* __restrict__ Hs,
    const float* __restrict__ Scmp, const int* __restrict__ smap,
    const float* __restrict__ W0, const float* __restrict__ W1, const float* __restrict__ W2,
    const int* __restrict__ cr, float* __restrict__ Cfix)
{
  const int count = cr[0];
  const int m0 = blockIdx.y * 128;
  if (m0 >= count) return;
  const int* rows = cr + 1;
  const int kbeg = blockIdx.z * FIX_KLEN;
  const int kend = kbeg + FIX_KLEN;

  __shared__ u16 sAh[128*LSTR];
  __shared__ u16 sAl[128*LSTR];
  __shared__ u16 sBh[128*LSTR];
  __shared__ u16 sBl[128*LSTR];

  const int tid = threadIdx.x;
  const int n0 = blockIdx.x * 128;
  int seg = n0 >> 10;
  const float* W = (seg==0) ? W0 : (seg==1 ? W1 : W2);
  int nw = n0 & 1023;

  const int wave = tid >> 6, lane = tid & 63;
  const int wm = wave >> 1, wn = wave & 1;
  const int l16 = lane & 15, lk8 = (lane >> 4) * 8;

  f32x4 acc[4][4];
  #pragma unroll
  for (int a=0;a<4;++a)
    #pragma unroll
    for (int b=0;b<4;++b) acc[a][b] = f32x4{0.f,0.f,0.f,0.f};

  for (int k0 = kbeg; k0 < kend; k0 += 32){
    #pragma unroll
    for (int i=0;i<4;++i){
      int flat = tid + i*256;
      int r  = flat >> 3;
      int c4 = flat & 7;
      int kk = k0 + c4*4;
      int mi = min(m0 + r, count-1);
      int mrow = rows[mi];
      const float* srcA;
      if (kk < 1024)      srcA = Xs + (size_t)mrow*1024 + kk;
      else if (kk < 3072) srcA = Hs + (size_t)mrow*2048 + (kk - 1024);
      else                srcA = Scmp + (size_t)smap[mrow]*2048 + (kk - 3072);
      f32x4 va = *(const f32x4*)srcA;
      f32x4 vb = *(const f32x4*)(W + (size_t)(nw + r)*5120 + kk);
      u16x4 ah, bh, al, bl;
      #pragma unroll
      for (int j=0;j<4;++j){
        u16 hA = f2bf(va[j]); ah[j] = hA; al[j] = f2bf(va[j] - bf2f(hA));
        u16 hB = f2bf(vb[j]); bh[j] = hB; bl[j] = f2bf(vb[j] - bf2f(hB));
      }
      int o = r*LSTR + c4*4;
      *(u16x4*)&sAh[o] = ah;
      *(u16x4*)&sBh[o] = bh;
      *(u16x4*)&sAl[o] = al;
      *(u16x4*)&sBl[o] = bl;
    }
    __syncthreads();
    bf16x8 fah[4], fbh[4], fal[4], fbl[4];
    #pragma unroll
    for (int f=0; f<4; ++f){
      int ra  = (wm*64 + f*16 + l16)*LSTR + lk8;
      int rb2 = (wn*64 + f*16 + l16)*LSTR + lk8;
      fah[f] = *(const bf16x8*)&sAh[ra];
      fbh[f] = *(const bf16x8*)&sBh[rb2];
      fal[f] = *(const bf16x8*)&sAl[ra];
      fbl[f] = *(const bf16x8*)&sBl[rb2];
    }
    #pragma unroll
    for (int fm=0; fm<4; ++fm){
      #pragma unroll
      for (int fn=0; fn<4; ++fn){
        acc[fm][fn] = __builtin_amdgcn_mfma_f32_16x16x32_bf16(fah[fm], fbh[fn], acc[fm][fn], 0,0,0);
        acc[fm][fn] = __builtin_amdgcn_mfma_f32_16x16x32_bf16(fal[fm], fbh[fn], acc[fm][fn], 0,0,0);
        acc[fm][fn] = __builtin_amdgcn_mfma_f32_16x16x32_bf16(fah[fm], fbl[fn], acc[fm][fn], 0,0,0);
      }
    }
    __syncthreads();
  }

  #pragma unroll
  for (int fm=0; fm<4; ++fm){
    int trow = wm*64 + fm*16 + (lane>>4)*4;
    #pragma unroll
    for (int fn=0; fn<4; ++fn){
      int lcol = wn*64 + fn*16 + l16;
      #pragma unroll
      for (int r2=0;r2<4;++r2){
        int mi = m0 + trow + r2;
        if (mi < count){
          atomicAdd(&Cfix[(size_t)mi*3072 + (n0 + lcol)], acc[fm][fn][r2]);
        }
      }
    }
  }
}

// ---------------- epilogue (flagged rows read compact rawfix + bias) ----------------
__global__ __launch_bounds__(256) void epilogue(
    const float* __restrict__ rawfio, const u16* __restrict__ rawg,
    const float* __restrict__ rawfix, const int* __restrict__ smap, const int* __restrict__ cr,
    const float* __restrict__ bf0, const float* __restrict__ bf1, const float* __restrict__ bf2,
    const float* __restrict__ c_prev, const float* __restrict__ d_prev,
    const float* __restrict__ b_prev, const float* __restrict__ theta,
    float* __restrict__ out)
{
  const int b = blockIdx.x;
  const int tid = threadIdx.x;
  float* Hout = out;
  float* Cout = out + (size_t)8388608;
  float* Dout = out + (size_t)16777216;
  float* Bout = out + (size_t)25165824;
  const float bp = b_prev[b];
  const float inv_t = 1.0f / (2.0f*bp + 1e-4f);
  float conv_acc = 0.f, emer_acc = 0.f;
  const size_t rb3 = (size_t)b*3072;
  const size_t rg = (size_t)b*2048;
  const int p = smap[b];
  const bool fx = (p >= 0 && p < cr[0]);
  const size_t rfx = (size_t)p*3072;

  #pragma unroll
  for (int j=0;j<4;++j){
    int h = tid + j*256;
    float fr, ir, og;
    if (fx){
      fr = rawfix[rfx + h]        + bf0[h];
      ir = rawfix[rfx + 1024 + h] + bf1[h];
      og = rawfix[rfx + 2048 + h] + bf2[h];
    } else {
      fr = rawfio[rb3 + h];
      ir = rawfio[rb3 + 1024 + h];
      og = rawfio[rb3 + 2048 + h];
    }
    float g0 = bf2f(rawg[rg + h]);
    float g1 = bf2f(rawg[rg + 1024 + h]);

    float mx = fmaxf(fr, fmaxf(ir, og));
    float ef = __expf((fr-mx)*inv_t);
    float ei = __expf((ir-mx)*inv_t);
    float eo = __expf((og-mx)*inv_t);
    float inv_s = 1.0f/(ef+ei+eo);
    float ft = ef*inv_s, it = ei*inv_s, ot = eo*inv_s;

    f32x2 cp = *(const f32x2*)(c_prev + 2*((size_t)b*1024 + h));
    f32x2 dp = *(const f32x2*)(d_prev + 2*((size_t)b*1024 + h));

    float r0 = (1.f-ft)*cp[0], r1 = (1.f-ft)*cp[1];
    float rm2 = r0*r0 + r1*r1;
    conv_acc += rm2 + 1e-8f;
    float rmag = sqrtf(rm2 + 1e-8f);
    float cm = __expf(0.66666667f * __logf(rmag));
    float rx = r0 + 1e-10f;
    float hr = fmaxf(sqrtf(rx*rx + r1*r1), 1e-30f);
    float invhr = cm / hr;
    float comp0 = fminf(fmaxf(rx*invhr, -10.f), 10.f);
    float comp1 = fminf(fmaxf(r1*invhr, -10.f), 10.f);

    float d0 = dp[0] + 0.01f*comp0;
    float d1 = dp[1] + 0.01f*comp1;
    float dmn = sqrtf(d0*d0 + d1*d1 + 1e-8f);
    if (dmn > 20.f){ float sc = 20.f/dmn; d0*=sc; d1*=sc; }

    float gt0 = ftanh(g0), gt1 = ftanh(g1);
    float cu0 = ft*cp[0] + it*gt0;
    float cu1 = ft*cp[1] + it*gt1;
    float th = theta[h];
    float sth, cth;
    __sincosf(th, &sth, &cth);
    float c0 = cth*cu0 - sth*cu1;
    float c1 = sth*cu0 + cth*cu1;
    float cs0 = ftanh(c0), cs1 = ftanh(c1);
    float hr0 = ot*cs0, hr1 = ot*cs1;

    float hx = hr0 + 1e-10f, dx = d0 + 1e-10f;
    float hh = sqrtf(hx*hx + hr1*hr1);
    float hd = sqrtf(dx*dx + d1*d1);
    float cosd = (hx*dx + hr1*d1) / fmaxf(hh*hd, 1e-30f);
    float G = 0.5f + 0.5f*cosd;
    float h0 = G*hr0, h1 = G*hr1;
    emer_acc += h0*h0 + h1*h1 + 1e-8f;

    h0 = (h0==h0)?h0:0.f;  h1 = (h1==h1)?h1:0.f;
    c0 = (c0==c0)?c0:0.f;  c1 = (c1==c1)?c1:0.f;
    d0 = (d0==d0)?d0:0.f;  d1 = (d1==d1)?d1:0.f;

    size_t oi = 2*((size_t)b*1024 + h);
    *(f32x2*)(Hout+oi) = f32x2{h0,h1};
    *(f32x2*)(Cout+oi) = f32x2{c0,c1};
    *(f32x2*)(Dout+oi) = f32x2{d0,d1};
  }

  #pragma unroll
  for (int off=32; off; off>>=1){
    conv_acc += __shfl_down(conv_acc, off);
    emer_acc += __shfl_down(emer_acc, off);
  }
  __shared__ float sred[8];
  int wv = tid>>6, ln = tid&63;
  if (ln==0){ sred[wv]=conv_acc; sred[4+wv]=emer_acc; }
  __syncthreads();
  if (tid==0){
    float cv = sred[0]+sred[1]+sred[2]+sred[3];
    float em = sred[4]+sred[5]+sred[6]+sred[7];
    float bm = cv/(cv+em+1e-8f);
    float bt = 0.99f*bp + 0.01f*bm;
    bt = (bt==bt)?bt:0.5f;
    Bout[b] = bt;
  }
}

extern "C" void kernel_launch(void* const* d_in, const int* in_sizes, int n_in,
                              void* d_out, int out_size, void* d_ws, size_t ws_size,
                              hipStream_t stream)
{
  const float* x_t    = (const float*)d_in[0];
  const float* h_prev = (const float*)d_in[1];
  const float* c_prev = (const float*)d_in[2];
  const float* d_prev = (const float*)d_in[3];
  const float* b_prev = (const float*)d_in[4];
  const float* Wf_w   = (const float*)d_in[5];
  const float* Wf_b   = (const float*)d_in[6];
  const float* Wi_w   = (const float*)d_in[7];
  const float* Wi_b   = (const float*)d_in[8];
  const float* Wo_w   = (const float*)d_in[9];
  const float* Wo_b   = (const float*)d_in[10];
  const float* Wc_w   = (const float*)d_in[11];
  const float* Wc_b   = (const float*)d_in[12];
  const float* Wr_w   = (const float*)d_in[13];
  const float* Wr_b   = (const float*)d_in[14];
  const float* theta  = (const float*)d_in[15];

  char* W = (char*)d_ws;
  float* rawfio = (float*)W;
  float* xc     = (float*)W;
  u16*   Wr_hi  = (u16*)(W + 50331648);
  u16*   Wr_lo  = (u16*)(W + 50331648 + 4194304);
  u16*   x_lo   = (u16*)(W + 50331648 + 8388608);
  u16*   raw_g  = (u16*)(W + 50331648);
  u16*   cA     = (u16*)(W + 67108864);
  u16*   WD     = (u16*)(W + 109051904);
  int*   idx    = (int*)(W + 140509184);
  int*   smap   = (int*)(W + 140509184 + 16388);
  float* Scmp   = (float*)(W + 140546048);
  float* rawfix = (float*)(W + 140546048 + (size_t)CAPF*2048*4);

  dim3 blk(256);

  prep0<<<15105, blk, 0, stream>>>(x_t, h_prev, cA, x_lo, Wr_w, Wr_hi, Wr_lo,
                                   b_prev, idx, smap, rawfix);
  gemm128<true,false,3><<<dim3(8,32), dim3(512), 0, stream>>>(
      cA, 5120, x_lo, 1024, Wr_hi, 1024, Wr_lo,
      Wr_b, xc, nullptr, 2048, 1024);
  prep_surf<<<16384, blk, 0, stream>>>(xc, d_prev, smap, Scmp, cA);
  gemm_fix_sk<<<dim3(24,8,FIX_KC), blk, 0, stream>>>(
      x_t, h_prev, Scmp, smap, Wf_w, Wi_w, Wo_w, idx, rawfix);
  cvtW3<<<15360, blk, 0, stream>>>(Wf_w, Wi_w, Wo_w, WD);
  // f/i/o merged: NR=3 -> BN=192, grid 16x16 = 256 blocks = exactly 1/CU (full fill)
  gemm8p<3,false,3><<<dim3(16,16), dim3(512), 0, stream>>>(
      cA, 5120, WD, 5120, Wf_b, Wi_b, Wo_b, rawfio, nullptr, 3072, 5120);
  cvt_hi<<<10240, blk, 0, stream>>>(Wc_w, WD, 2621440);
  gemm128<false,true,5><<<dim3(8,32), dim3(512), 0, stream>>>(
      cA, 5120, nullptr, 0, WD, 5120, nullptr,
      Wc_b, nullptr, raw_g, 2048, 5120);
  epilogue<<<4096, blk, 0, stream>>>(rawfio, raw_g, rawfix, smap, idx,
                                     Wf_b, Wi_b, Wo_b,
                                     c_prev, d_prev, b_prev, theta, (float*)d_out);
}